// Round 2
// baseline (2691.494 us; speedup 1.0000x reference)
//
#include <hip/hip_runtime.h>

#define NB 16
#define NN 8192
#define NS 1024
#define NK 32
#define NR (NB*NS*NK)   // 524288 rows through the MLP

#define NFPS 16          // fps blocks (one per batch)
#define NWORK 240        // persistent worker blocks (ballquery + stats1)
#define NWAVES (NWORK*8) // 1920 worker waves

static __device__ __forceinline__ int brev6(int l) {
  return ((l&1)<<5)|((l&2)<<3)|((l&4)<<1)|((l&8)>>1)|((l&16)>>3)|((l&32)>>5);
}

// pack two f32 -> two bf16 (RNE) in one uint (low = first)
static __device__ __forceinline__ unsigned pack_bf2(float a, float b) {
  unsigned ua = __float_as_uint(a), ub = __float_as_uint(b);
  ua += 0x7fffu + ((ua >> 16) & 1u);
  ub += 0x7fffu + ((ub >> 16) & 1u);
  return (ua >> 16) | (ub & 0xffff0000u);
}
static __device__ __forceinline__ float bf_lo(unsigned u) { return __uint_as_float(u << 16); }
static __device__ __forceinline__ float bf_hi(unsigned u) { return __uint_as_float(u & 0xffff0000u); }

// ---------------------------------------------------------------------------
// FUSED fps + ballquery + stats1 (UNCHANGED from round 1 — proven at 1109us,
// passes). blocks 0..15 FPS producers, 16..255 persistent workers spinning on
// the NaN sentinel. 98.8KB LDS forces 1 block/CU; grid 256 <= 256 CUs so all
// blocks co-resident (harness-proven).
// ---------------------------------------------------------------------------
__global__ __launch_bounds__(512, 1) void fps_bq_s1_kernel(
    const float* __restrict__ xyz, const float* __restrict__ pts,
    const float* __restrict__ w1,  const float* __restrict__ b1,
    float* __restrict__ new_xyz,   float* __restrict__ x0,
    float* __restrict__ part)
{
  __shared__ float sx[NN], sy[NN], sz[NN];
  __shared__ unsigned long long s_wb[2][8];

  if (blockIdx.x < NFPS) {
    // ------------------------- FPS producer -------------------------
    const int b = blockIdx.x;
    const int t = threadIdx.x;
    const int lane = t & 63;
    const int wv = t >> 6;
    const float* base = xyz + (size_t)b * NN * 3;

    float px[16], py[16], pz[16], dist[16];
#pragma unroll
    for (int j = 0; j < 16; ++j) {
      int p = j * 512 + t;
      float x = base[p*3+0], y = base[p*3+1], z = base[p*3+2];
      px[j] = x; py[j] = y; pz[j] = z; dist[j] = 1e10f;
      sx[p] = x; sy[p] = y; sz[p] = z;
    }
    __syncthreads();

    float cx = sx[0], cy = sy[0], cz = sz[0];
    unsigned* outp = (unsigned*)(new_xyz + (size_t)b * NS * 3);
    if (t == 0) {
      __hip_atomic_store(outp+0, __float_as_uint(cx), __ATOMIC_RELAXED, __HIP_MEMORY_SCOPE_AGENT);
      __hip_atomic_store(outp+1, __float_as_uint(cy), __ATOMIC_RELAXED, __HIP_MEMORY_SCOPE_AGENT);
      __hip_atomic_store(outp+2, __float_as_uint(cz), __ATOMIC_RELAXED, __HIP_MEMORY_SCOPE_AGENT);
    }

    for (int s = 1; s < NS; ++s) {
      const int par = s & 1;
      float bestv = -1.0f;
#pragma unroll
      for (int j = 0; j < 16; ++j) {
        float dx = px[j]-cx, dy = py[j]-cy, dz = pz[j]-cz;
        float d = __fadd_rn(__fadd_rn(__fmul_rn(dx,dx),__fmul_rn(dy,dy)),__fmul_rn(dz,dz));
        float nd = fminf(dist[j], d);
        dist[j] = nd;
        bestv = fmaxf(bestv, nd);
      }
      float wmax = bestv;
#pragma unroll
      for (int off = 32; off >= 1; off >>= 1)
        wmax = fmaxf(wmax, __shfl_xor(wmax, off, 64));
      int minj = 0;
#pragma unroll
      for (int j = 15; j >= 0; --j) if (dist[j] == wmax) minj = j;
      const int myidx = minj * 512 + t;
      const unsigned long long mask = __ballot(bestv == wmax);
      int l0 = __ffsll((unsigned long long)mask) - 1;
      int widx = __shfl(myidx, l0, 64);
      if (__popcll(mask) > 1) {
        unsigned long long m = mask & (mask - 1);
        while (m) {
          int l = __ffsll((unsigned long long)m) - 1;
          int v = __shfl(myidx, l, 64);
          widx = min(widx, v);
          m &= m - 1;
        }
      }
      if (lane == 0)
        s_wb[par][wv] = ((unsigned long long)__float_as_uint(wmax) << 32)
                        | (unsigned)(8191 - widx);
      __syncthreads();
      unsigned long long gk = s_wb[par][0];
#pragma unroll
      for (int i = 1; i < 8; ++i) {
        unsigned long long ki = s_wb[par][i]; if (ki > gk) gk = ki;
      }
      const int bi = 8191 - (int)(gk & 0xffffull);
      cx = sx[bi]; cy = sy[bi]; cz = sz[bi];
      if (t == 0) {
        unsigned* o = outp + s*3;
        __hip_atomic_store(o+0, __float_as_uint(cx), __ATOMIC_RELAXED, __HIP_MEMORY_SCOPE_AGENT);
        __hip_atomic_store(o+1, __float_as_uint(cy), __ATOMIC_RELAXED, __HIP_MEMORY_SCOPE_AGENT);
        __hip_atomic_store(o+2, __float_as_uint(cz), __ATOMIC_RELAXED, __HIP_MEMORY_SCOPE_AGENT);
      }
    }
  } else {
    // --------------------- persistent BQ+stats1 workers ---------------------
    const int wid  = ((int)blockIdx.x - NFPS) * 8 + (threadIdx.x >> 6);
    const int lane = threadIdx.x & 63;
    float wrow[6];
#pragma unroll
    for (int c = 0; c < 6; ++c) wrow[c] = w1[lane*6 + c];
    const float bv = b1[lane];
    const float R2 = 0.04f;

    for (int item = wid; item < NB*NS; item += NWAVES) {
      const int s = item >> 4;        // s-major: early centroids first
      const int b = item & 15;
      const int gw = (b << 10) + s;
      const float* base  = xyz + (size_t)b * NN * 3;
      const float* pbase = pts + (size_t)b * NN * 3;
      float* out = x0 + (size_t)gw * (NK*6);

      const unsigned* cp = (const unsigned*)(new_xyz + (size_t)gw * 3);
      float cx, cy, cz;
      for (;;) {
        unsigned ux = __hip_atomic_load(cp+0, __ATOMIC_RELAXED, __HIP_MEMORY_SCOPE_AGENT);
        unsigned uy = __hip_atomic_load(cp+1, __ATOMIC_RELAXED, __HIP_MEMORY_SCOPE_AGENT);
        unsigned uz = __hip_atomic_load(cp+2, __ATOMIC_RELAXED, __HIP_MEMORY_SCOPE_AGENT);
        if (ux != 0xFFFFFFFFu && uy != 0xFFFFFFFFu && uz != 0xFFFFFFFFu) {
          cx = __uint_as_float(ux); cy = __uint_as_float(uy); cz = __uint_as_float(uz);
          break;
        }
        __builtin_amdgcn_s_sleep(16);
      }

      const float t1 = __fadd_rn(__fadd_rn(__fmul_rn(cx,cx),__fmul_rn(cy,cy)),__fmul_rn(cz,cz));
      int count = 0, pfirst = 0;
      for (int n0 = 0; n0 < NN; n0 += 64) {
        const int p = n0 + lane;
        const float ax = base[p*3], ay = base[p*3+1], az = base[p*3+2];
        const float t2 = __fadd_rn(__fadd_rn(__fmul_rn(ax,ax),__fmul_rn(ay,ay)),__fmul_rn(az,az));
        const float dt = __fmaf_rn(cz, az, __fmaf_rn(cy, ay, __fmul_rn(cx, ax)));
        const float sq = __fadd_rn(__fsub_rn(t1, __fmul_rn(2.0f,dt)), t2);
        const bool keep = !(sq > R2);
        const unsigned long long mask = __ballot(keep);
        const int slot = count + __popcll(mask & ((1ull<<lane)-1ull));
        if (keep && slot < NK) {
          float* o = out + slot*6;
          o[0]=ax-cx; o[1]=ay-cy; o[2]=az-cz;
          o[3]=pbase[p*3]; o[4]=pbase[p*3+1]; o[5]=pbase[p*3+2];
        }
        if (count == 0 && mask != 0ull) pfirst = n0 + (__ffsll((unsigned long long)mask) - 1);
        count += __popcll(mask);
        if (count >= NK) break;
      }
      if (count < NK) {
        const float* fx = base + (size_t)pfirst*3;
        const float* fp = pbase + (size_t)pfirst*3;
        const float a0 = fx[0]-cx, a1 = fx[1]-cy, a2 = fx[2]-cz;
        const float a3 = fp[0], a4 = fp[1], a5 = fp[2];
        for (int sl = count + lane; sl < NK; sl += 64) {
          float* o = out + sl*6;
          o[0]=a0;o[1]=a1;o[2]=a2;o[3]=a3;o[4]=a4;o[5]=a5;
        }
      }

      __threadfence_block();
      float sAcc = 0.f, qAcc = 0.f;
#pragma unroll 4
      for (int k = 0; k < NK; ++k) {
        const float* row = out + k*6;
        float z = bv;
#pragma unroll
        for (int c = 0; c < 6; ++c) z = fmaf(row[c], wrow[c], z);
        sAcc += z;
        qAcc = fmaf(z, z, qAcc);
      }
      part[(size_t)gw*128 + lane]      = sAcc;
      part[(size_t)gw*128 + 64 + lane] = qAcc;
    }
  }
}

// ---------------------------------------------------------------------------
// butterfly64: z[0] = wave sum of channel brev6(lane).
// ---------------------------------------------------------------------------
__device__ __forceinline__ void butterfly64(float (&z)[64], float (&q)[64], int lane) {
#pragma unroll
  for (int d = 0; d < 6; ++d) {
    const int m = 32 >> d;
    const bool hi = (lane >> d) & 1;
#pragma unroll
    for (int i = 0; i < m; ++i) {
      float sv = hi ? z[i] : z[i+m];
      float rv = __shfl_xor(sv, 1<<d, 64);
      z[i] = (hi ? z[i+m] : z[i]) + rv;
      float sq = hi ? q[i] : q[i+m];
      float rq = __shfl_xor(sq, 1<<d, 64);
      q[i] = (hi ? q[i+m] : q[i]) + rq;
    }
  }
}

__device__ __forceinline__ void lean_h1(const float* __restrict__ xr,
                                        const float* __restrict__ w1,
                                        const float* __restrict__ b1,
                                        const float* __restrict__ ab1,
                                        float (&h)[64]) {
  float x[6];
#pragma unroll
  for (int c = 0; c < 6; ++c) x[c] = xr[c];
#pragma unroll
  for (int o = 0; o < 64; ++o) {
    float acc = b1[o];
#pragma unroll
    for (int c = 0; c < 6; ++c) acc = fmaf(x[c], w1[o*6+c], acc);
    h[o] = fmaxf(0.f, fmaf(acc, ab1[o], ab1[64+o]));
  }
}

// ---------------------------------------------------------------------------
// Software grid barrier for the 256-block tail kernel. Safe because the
// 141KB LDS forces 1 block/CU and grid = 256 <= 256 CUs -> all co-resident
// (same structural argument as the fused kernel, harness-proven in round 1).
// Fresh counter per barrier instance (memset to 0 each launch) -> no sense
// reversal needed. ACQ_REL RMW + ACQUIRE spin load at AGENT scope: the
// release sequence through the RMW chain makes ALL arrivers' prior writes
// visible to every block that observes count==256.
// ---------------------------------------------------------------------------
__device__ __forceinline__ void gridbar(unsigned* bar, int idx) {
  __syncthreads();
  if (threadIdx.x == 0) {
    __hip_atomic_fetch_add(&bar[idx], 1u, __ATOMIC_ACQ_REL, __HIP_MEMORY_SCOPE_AGENT);
    unsigned v;
    do {
      __builtin_amdgcn_s_sleep(1);
      v = __hip_atomic_load(&bar[idx], __ATOMIC_ACQUIRE, __HIP_MEMORY_SCOPE_AGENT);
    } while (v < 256u);
  }
  __syncthreads();
}

// BN finalize phase (runs on blocks [0,C); 512 threads). Same double-precision
// math as the proven finalize_kernel.
__device__ __forceinline__ void fin_phase(const float* __restrict__ part, int nrows,
                                          int rowstride, int C,
                                          const float* __restrict__ g,
                                          const float* __restrict__ be,
                                          float* __restrict__ ab,
                                          double* ls, double* lq) {
  const int ch = blockIdx.x;
  const int t = threadIdx.x;
  const int qo = rowstride >> 1;
  double s = 0.0, q = 0.0;
  for (int wv = t; wv < nrows; wv += 512) {
    s += (double)part[(size_t)wv*rowstride + ch];
    q += (double)part[(size_t)wv*rowstride + qo + ch];
  }
#pragma unroll
  for (int off = 32; off >= 1; off >>= 1) {
    s += __shfl_down(s, off, 64);
    q += __shfl_down(q, off, 64);
  }
  if ((t & 63) == 0) { ls[t>>6] = s; lq[t>>6] = q; }
  __syncthreads();
  if (t == 0) {
    double S = 0.0, Q = 0.0;
#pragma unroll
    for (int i = 0; i < 8; ++i) { S += ls[i]; Q += lq[i]; }
    double mean = S / (double)NR;
    double var  = Q / (double)NR - mean*mean;
    double inv  = 1.0 / sqrt(var + 1e-5);
    double gg   = (double)g[ch];
    ab[ch]     = (float)(gg * inv);
    ab[C + ch] = (float)((double)be[ch] - mean * gg * inv);
  }
}

// ---------------------------------------------------------------------------
// TAIL: the entire post-FPS chain in ONE persistent kernel.
//   fin1 -> B0 -> stats2(+bf16 z2 store) -> B1 -> fin2 -> B2 ->
//   stats3(tile max/min/sum/sumsq) -> B3 -> fin3 -> B4 -> bn3.
// 256 blocks x 512 threads; 141,312B LDS (stats3 tile 512x65 + gs/gq union
// with finalize double scratch) -> 1 block/CU, co-resident, barrier-safe.
// stats2 streams z per-output (no z[64]+q[64] arrays live together) to stay
// under the 256-VGPR cap of 512-thread blocks.
// ---------------------------------------------------------------------------
__global__ __launch_bounds__(512, 1) void tail_kernel(
    const float* __restrict__ x0,
    const float* __restrict__ w1, const float* __restrict__ b1,
    const float* __restrict__ g1, const float* __restrict__ be1,
    const float* __restrict__ w2, const float* __restrict__ b2,
    const float* __restrict__ g2, const float* __restrict__ be2,
    const float* __restrict__ w3, const float* __restrict__ b3,
    const float* __restrict__ g3, const float* __restrict__ be3,
    float* __restrict__ part, float* __restrict__ ab,
    unsigned* __restrict__ z2u, float* __restrict__ kmx,
    float* __restrict__ kmn, float* __restrict__ new_points,
    unsigned* __restrict__ bar)
{
  __shared__ double smem[17664];               // 141,312 B
  float* tile = (float*)smem;                  // [512][65] (stats3)
  float* gs   = (float*)smem + 512*65;         // [16][64]
  float* gq   = gs + 16*64;                    // [16][64]
  double* ls  = smem;                          // [8] (finalize scratch, aliased)
  double* lq  = smem + 8;                      // [8]

  const int t = threadIdx.x;
  const int lane = t & 63;
  const int wvi = t >> 6;                      // 0..7
  float* ab1 = ab; float* ab2 = ab + 128; float* ab3 = ab + 256;

  // ---- fin1: BN1 stats from per-item partials (16384 x 128) ----
  if (blockIdx.x < 64)
    fin_phase(part, NB*NS, 128, 64, g1, be1, ab1, ls, lq);
  gridbar(bar, 0);

  // ---- stats2: 4 rows/thread; z2 -> bf16; wave partial sums ----
  {
    float sz[64], sq[64];
#pragma unroll
    for (int o = 0; o < 64; ++o) { sz[o] = 0.f; sq[o] = 0.f; }
#pragma unroll 1
    for (int k = 0; k < 4; ++k) {
      const int row = (int)blockIdx.x*512 + t + k*131072;
      float h[64];
      lean_h1(x0 + (size_t)row*6, w1, b1, ab1, h);
      uint4* zw = (uint4*)(z2u + (size_t)row * 32);
#pragma unroll
      for (int i = 0; i < 8; ++i) {
        float z8[8];
#pragma unroll
        for (int j = 0; j < 8; ++j) {
          const int o = i*8 + j;
          float acc = b2[o];
#pragma unroll
          for (int c = 0; c < 64; ++c) acc = fmaf(h[c], w2[o*64+c], acc);
          z8[j] = acc;
          sz[o] += acc;
          sq[o] = fmaf(acc, acc, sq[o]);
        }
        zw[i] = make_uint4(pack_bf2(z8[0],z8[1]), pack_bf2(z8[2],z8[3]),
                           pack_bf2(z8[4],z8[5]), pack_bf2(z8[6],z8[7]));
      }
    }
    butterfly64(sz, sq, lane);
    const int wg = (int)blockIdx.x*8 + wvi;    // 2048 part rows, one per wave
    const int ch = brev6(lane);
    part[(size_t)wg*128 + ch]      = sz[0];
    part[(size_t)wg*128 + 64 + ch] = sq[0];
  }
  gridbar(bar, 1);

  if (blockIdx.x < 64)
    fin_phase(part, 2048, 128, 64, g2, be2, ab2, ls, lq);
  gridbar(bar, 2);

  // ---- stats3: 4 passes of 512-row tiles; kmax/kmin + BN3 partials ----
  {
    float totS0 = 0.f, totS1 = 0.f, totQ0 = 0.f, totQ1 = 0.f;
#pragma unroll 1
    for (int pass = 0; pass < 4; ++pass) {
      const int row = (int)blockIdx.x*2048 + pass*512 + t;
      const uint4* zr = (const uint4*)(z2u + (size_t)row * 32);
      float h[64];
#pragma unroll
      for (int i = 0; i < 8; ++i) {
        uint4 v = zr[i];
        const int c = i*8;
        h[c+0]=fmaxf(0.f,fmaf(bf_lo(v.x),ab2[c+0],ab2[64+c+0]));
        h[c+1]=fmaxf(0.f,fmaf(bf_hi(v.x),ab2[c+1],ab2[64+c+1]));
        h[c+2]=fmaxf(0.f,fmaf(bf_lo(v.y),ab2[c+2],ab2[64+c+2]));
        h[c+3]=fmaxf(0.f,fmaf(bf_hi(v.y),ab2[c+3],ab2[64+c+3]));
        h[c+4]=fmaxf(0.f,fmaf(bf_lo(v.z),ab2[c+4],ab2[64+c+4]));
        h[c+5]=fmaxf(0.f,fmaf(bf_hi(v.z),ab2[c+5],ab2[64+c+5]));
        h[c+6]=fmaxf(0.f,fmaf(bf_lo(v.w),ab2[c+6],ab2[64+c+6]));
        h[c+7]=fmaxf(0.f,fmaf(bf_hi(v.w),ab2[c+7],ab2[64+c+7]));
      }
#pragma unroll 1
      for (int chunk = 0; chunk < 2; ++chunk) {
#pragma unroll
        for (int o = 0; o < 64; ++o) {
          float acc = b3[chunk*64 + o];
          const float* wr = w3 + (size_t)(chunk*64 + o) * 64;
#pragma unroll
          for (int c = 0; c < 64; ++c) acc = fmaf(h[c], wr[c], acc);
          tile[t*65 + o] = acc;
        }
        __syncthreads();
        // wave wvi reduces groups 2*wvi, 2*wvi+1 (16 groups of 32 rows)
#pragma unroll
        for (int i2 = 0; i2 < 2; ++i2) {
          const int g = wvi*2 + i2;
          float m = -1e30f, n = 1e30f, s = 0.f, q = 0.f;
#pragma unroll
          for (int k = 0; k < 32; ++k) {
            float v = tile[(g*32 + k)*65 + lane];
            m = fmaxf(m, v); n = fminf(n, v); s += v; q = fmaf(v, v, q);
          }
          const size_t group = (size_t)blockIdx.x*64 + pass*16 + g;
          kmx[group*128 + chunk*64 + lane] = m;
          kmn[group*128 + chunk*64 + lane] = n;
          gs[g*64 + lane] = s; gq[g*64 + lane] = q;
        }
        __syncthreads();
        if (t < 128) {
          const int c = t & 63;
          float tot = 0.f;
          if (t < 64) {
#pragma unroll
            for (int g = 0; g < 16; ++g) tot += gs[g*64 + c];
            if (chunk == 0) totS0 += tot; else totS1 += tot;
          } else {
#pragma unroll
            for (int g = 0; g < 16; ++g) tot += gq[g*64 + c];
            if (chunk == 0) totQ0 += tot; else totQ1 += tot;
          }
        }
        __syncthreads();
      }
    }
    // part rows: 256 x 256 -> [sum(c0..c63), sum(c64..c127), sq(...), sq(...)]
    if (t < 64) {
      part[(size_t)blockIdx.x*256 + t]      = totS0;
      part[(size_t)blockIdx.x*256 + 64 + t] = totS1;
    } else if (t < 128) {
      part[(size_t)blockIdx.x*256 + 128 + (t-64)] = totQ0;
      part[(size_t)blockIdx.x*256 + 192 + (t-64)] = totQ1;
    }
  }
  gridbar(bar, 3);

  if (blockIdx.x < 128)
    fin_phase(part, 256, 256, 128, g3, be3, ab3, ls, lq);
  gridbar(bar, 4);

  // ---- bn3: out = relu(a*sel + b), sel = a>=0 ? kmax : kmin ----
#pragma unroll 1
  for (int k = 0; k < 16; ++k) {
    const size_t idx = (size_t)k*131072 + (size_t)blockIdx.x*512 + t;
    const int c = (int)(idx & 127);
    const float a = ab3[c], bsh = ab3[128 + c];
    const float v = (a >= 0.f) ? kmx[idx] : kmn[idx];
    new_points[idx] = fmaxf(0.f, fmaf(v, a, bsh));
  }
}

// ============================ launcher ============================

extern "C" void kernel_launch(void* const* d_in, const int* in_sizes, int n_in,
                              void* d_out, int out_size, void* d_ws, size_t ws_size,
                              hipStream_t stream) {
  (void)in_sizes; (void)n_in; (void)out_size; (void)ws_size;
  const float* xyz = (const float*)d_in[0];
  const float* pts = (const float*)d_in[1];
  const float* w1  = (const float*)d_in[2];
  const float* b1  = (const float*)d_in[3];
  const float* g1  = (const float*)d_in[4];
  const float* be1 = (const float*)d_in[5];
  const float* w2  = (const float*)d_in[6];
  const float* b2  = (const float*)d_in[7];
  const float* g2  = (const float*)d_in[8];
  const float* be2 = (const float*)d_in[9];
  const float* w3  = (const float*)d_in[10];
  const float* b3  = (const float*)d_in[11];
  const float* g3  = (const float*)d_in[12];
  const float* be3 = (const float*)d_in[13];

  float* out = (float*)d_out;
  float* new_xyz    = out;
  float* new_points = out + NB*NS*3;

  // ws: x0 12.6MB | part 8.4MB | ab 2KB | z2u 67MB | kmx 8MB | kmn 8MB | bar
  float* ws = (float*)d_ws;
  float* x0   = ws;                               // NR*6
  float* part = x0 + (size_t)NR*6;                // 2097152 floats (16384*128)
  float* ab   = part + 2097152;                   // 512
  unsigned* z2u = (unsigned*)(ab + 512);          // NR*32 u32
  float* kmx = (float*)(z2u + (size_t)NR*32);     // 16384*128
  float* kmn = kmx + (size_t)16384*128;           // 16384*128
  unsigned* bar = (unsigned*)(kmn + (size_t)16384*128); // 8 u32 barrier ctrs

  // NaN-poison new_xyz (publish sentinel) + zero barrier counters.
  (void)hipMemsetAsync(new_xyz, 0xFF, (size_t)NB*NS*3*sizeof(float), stream);
  (void)hipMemsetAsync(bar, 0, 8*sizeof(unsigned), stream);

  hipLaunchKernelGGL(fps_bq_s1_kernel, dim3(NFPS + NWORK), dim3(512), 0, stream,
                     xyz, pts, w1, b1, new_xyz, x0, part);

  hipLaunchKernelGGL(tail_kernel, dim3(256), dim3(512), 0, stream,
                     x0, w1, b1, g1, be1, w2, b2, g2, be2, w3, b3, g3, be3,
                     part, ab, z2u, kmx, kmn, new_points, bar);
}

// Round 3
// 2457.805 us; speedup vs baseline: 1.0951x; 1.0951x over previous
//
#include <hip/hip_runtime.h>

#define NB 16
#define NN 8192
#define NS 1024
#define NK 32
#define NR (NB*NS*NK)   // 524288 rows through the MLP

#define NFPS 16          // fps blocks (one per batch)
#define NWORK 240        // persistent worker blocks (ballquery + stats1)
#define NWAVES (NWORK*8) // 1920 worker waves

static __device__ __forceinline__ int brev6(int l) {
  return ((l&1)<<5)|((l&2)<<3)|((l&4)<<1)|((l&8)>>1)|((l&16)>>3)|((l&32)>>5);
}

// pack two f32 -> two bf16 (RNE) in one uint (low = first)
static __device__ __forceinline__ unsigned pack_bf2(float a, float b) {
  unsigned ua = __float_as_uint(a), ub = __float_as_uint(b);
  ua += 0x7fffu + ((ua >> 16) & 1u);
  ub += 0x7fffu + ((ub >> 16) & 1u);
  return (ua >> 16) | (ub & 0xffff0000u);
}
static __device__ __forceinline__ float bf_lo(unsigned u) { return __uint_as_float(u << 16); }
static __device__ __forceinline__ float bf_hi(unsigned u) { return __uint_as_float(u & 0xffff0000u); }

// ---------------------------------------------------------------------------
// FUSED fps + ballquery + stats1 (UNCHANGED — proven 1109us, passes).
// ---------------------------------------------------------------------------
__global__ __launch_bounds__(512, 1) void fps_bq_s1_kernel(
    const float* __restrict__ xyz, const float* __restrict__ pts,
    const float* __restrict__ w1,  const float* __restrict__ b1,
    float* __restrict__ new_xyz,   float* __restrict__ x0,
    float* __restrict__ part)
{
  __shared__ float sx[NN], sy[NN], sz[NN];
  __shared__ unsigned long long s_wb[2][8];

  if (blockIdx.x < NFPS) {
    // ------------------------- FPS producer -------------------------
    const int b = blockIdx.x;
    const int t = threadIdx.x;
    const int lane = t & 63;
    const int wv = t >> 6;
    const float* base = xyz + (size_t)b * NN * 3;

    float px[16], py[16], pz[16], dist[16];
#pragma unroll
    for (int j = 0; j < 16; ++j) {
      int p = j * 512 + t;
      float x = base[p*3+0], y = base[p*3+1], z = base[p*3+2];
      px[j] = x; py[j] = y; pz[j] = z; dist[j] = 1e10f;
      sx[p] = x; sy[p] = y; sz[p] = z;
    }
    __syncthreads();

    float cx = sx[0], cy = sy[0], cz = sz[0];
    unsigned* outp = (unsigned*)(new_xyz + (size_t)b * NS * 3);
    if (t == 0) {
      __hip_atomic_store(outp+0, __float_as_uint(cx), __ATOMIC_RELAXED, __HIP_MEMORY_SCOPE_AGENT);
      __hip_atomic_store(outp+1, __float_as_uint(cy), __ATOMIC_RELAXED, __HIP_MEMORY_SCOPE_AGENT);
      __hip_atomic_store(outp+2, __float_as_uint(cz), __ATOMIC_RELAXED, __HIP_MEMORY_SCOPE_AGENT);
    }

    for (int s = 1; s < NS; ++s) {
      const int par = s & 1;
      float bestv = -1.0f;
#pragma unroll
      for (int j = 0; j < 16; ++j) {
        float dx = px[j]-cx, dy = py[j]-cy, dz = pz[j]-cz;
        float d = __fadd_rn(__fadd_rn(__fmul_rn(dx,dx),__fmul_rn(dy,dy)),__fmul_rn(dz,dz));
        float nd = fminf(dist[j], d);
        dist[j] = nd;
        bestv = fmaxf(bestv, nd);
      }
      float wmax = bestv;
#pragma unroll
      for (int off = 32; off >= 1; off >>= 1)
        wmax = fmaxf(wmax, __shfl_xor(wmax, off, 64));
      int minj = 0;
#pragma unroll
      for (int j = 15; j >= 0; --j) if (dist[j] == wmax) minj = j;
      const int myidx = minj * 512 + t;
      const unsigned long long mask = __ballot(bestv == wmax);
      int l0 = __ffsll((unsigned long long)mask) - 1;
      int widx = __shfl(myidx, l0, 64);
      if (__popcll(mask) > 1) {
        unsigned long long m = mask & (mask - 1);
        while (m) {
          int l = __ffsll((unsigned long long)m) - 1;
          int v = __shfl(myidx, l, 64);
          widx = min(widx, v);
          m &= m - 1;
        }
      }
      if (lane == 0)
        s_wb[par][wv] = ((unsigned long long)__float_as_uint(wmax) << 32)
                        | (unsigned)(8191 - widx);
      __syncthreads();
      unsigned long long gk = s_wb[par][0];
#pragma unroll
      for (int i = 1; i < 8; ++i) {
        unsigned long long ki = s_wb[par][i]; if (ki > gk) gk = ki;
      }
      const int bi = 8191 - (int)(gk & 0xffffull);
      cx = sx[bi]; cy = sy[bi]; cz = sz[bi];
      if (t == 0) {
        unsigned* o = outp + s*3;
        __hip_atomic_store(o+0, __float_as_uint(cx), __ATOMIC_RELAXED, __HIP_MEMORY_SCOPE_AGENT);
        __hip_atomic_store(o+1, __float_as_uint(cy), __ATOMIC_RELAXED, __HIP_MEMORY_SCOPE_AGENT);
        __hip_atomic_store(o+2, __float_as_uint(cz), __ATOMIC_RELAXED, __HIP_MEMORY_SCOPE_AGENT);
      }
    }
  } else {
    // --------------------- persistent BQ+stats1 workers ---------------------
    const int wid  = ((int)blockIdx.x - NFPS) * 8 + (threadIdx.x >> 6);
    const int lane = threadIdx.x & 63;
    float wrow[6];
#pragma unroll
    for (int c = 0; c < 6; ++c) wrow[c] = w1[lane*6 + c];
    const float bv = b1[lane];
    const float R2 = 0.04f;

    for (int item = wid; item < NB*NS; item += NWAVES) {
      const int s = item >> 4;        // s-major: early centroids first
      const int b = item & 15;
      const int gw = (b << 10) + s;
      const float* base  = xyz + (size_t)b * NN * 3;
      const float* pbase = pts + (size_t)b * NN * 3;
      float* out = x0 + (size_t)gw * (NK*6);

      const unsigned* cp = (const unsigned*)(new_xyz + (size_t)gw * 3);
      float cx, cy, cz;
      for (;;) {
        unsigned ux = __hip_atomic_load(cp+0, __ATOMIC_RELAXED, __HIP_MEMORY_SCOPE_AGENT);
        unsigned uy = __hip_atomic_load(cp+1, __ATOMIC_RELAXED, __HIP_MEMORY_SCOPE_AGENT);
        unsigned uz = __hip_atomic_load(cp+2, __ATOMIC_RELAXED, __HIP_MEMORY_SCOPE_AGENT);
        if (ux != 0xFFFFFFFFu && uy != 0xFFFFFFFFu && uz != 0xFFFFFFFFu) {
          cx = __uint_as_float(ux); cy = __uint_as_float(uy); cz = __uint_as_float(uz);
          break;
        }
        __builtin_amdgcn_s_sleep(16);
      }

      const float t1 = __fadd_rn(__fadd_rn(__fmul_rn(cx,cx),__fmul_rn(cy,cy)),__fmul_rn(cz,cz));
      int count = 0, pfirst = 0;
      for (int n0 = 0; n0 < NN; n0 += 64) {
        const int p = n0 + lane;
        const float ax = base[p*3], ay = base[p*3+1], az = base[p*3+2];
        const float t2 = __fadd_rn(__fadd_rn(__fmul_rn(ax,ax),__fmul_rn(ay,ay)),__fmul_rn(az,az));
        const float dt = __fmaf_rn(cz, az, __fmaf_rn(cy, ay, __fmul_rn(cx, ax)));
        const float sq = __fadd_rn(__fsub_rn(t1, __fmul_rn(2.0f,dt)), t2);
        const bool keep = !(sq > R2);
        const unsigned long long mask = __ballot(keep);
        const int slot = count + __popcll(mask & ((1ull<<lane)-1ull));
        if (keep && slot < NK) {
          float* o = out + slot*6;
          o[0]=ax-cx; o[1]=ay-cy; o[2]=az-cz;
          o[3]=pbase[p*3]; o[4]=pbase[p*3+1]; o[5]=pbase[p*3+2];
        }
        if (count == 0 && mask != 0ull) pfirst = n0 + (__ffsll((unsigned long long)mask) - 1);
        count += __popcll(mask);
        if (count >= NK) break;
      }
      if (count < NK) {
        const float* fx = base + (size_t)pfirst*3;
        const float* fp = pbase + (size_t)pfirst*3;
        const float a0 = fx[0]-cx, a1 = fx[1]-cy, a2 = fx[2]-cz;
        const float a3 = fp[0], a4 = fp[1], a5 = fp[2];
        for (int sl = count + lane; sl < NK; sl += 64) {
          float* o = out + sl*6;
          o[0]=a0;o[1]=a1;o[2]=a2;o[3]=a3;o[4]=a4;o[5]=a5;
        }
      }

      __threadfence_block();
      float sAcc = 0.f, qAcc = 0.f;
#pragma unroll 4
      for (int k = 0; k < NK; ++k) {
        const float* row = out + k*6;
        float z = bv;
#pragma unroll
        for (int c = 0; c < 6; ++c) z = fmaf(row[c], wrow[c], z);
        sAcc += z;
        qAcc = fmaf(z, z, qAcc);
      }
      part[(size_t)gw*128 + lane]      = sAcc;
      part[(size_t)gw*128 + 64 + lane] = qAcc;
    }
  }
}

// ---------------------------------------------------------------------------
// butterfly64: z[0] = wave sum of channel brev6(lane).
// ---------------------------------------------------------------------------
__device__ __forceinline__ void butterfly64(float (&z)[64], float (&q)[64], int lane) {
#pragma unroll
  for (int d = 0; d < 6; ++d) {
    const int m = 32 >> d;
    const bool hi = (lane >> d) & 1;
#pragma unroll
    for (int i = 0; i < m; ++i) {
      float sv = hi ? z[i] : z[i+m];
      float rv = __shfl_xor(sv, 1<<d, 64);
      z[i] = (hi ? z[i+m] : z[i]) + rv;
      float sq = hi ? q[i] : q[i+m];
      float rq = __shfl_xor(sq, 1<<d, 64);
      q[i] = (hi ? q[i+m] : q[i]) + rq;
    }
  }
}

__device__ __forceinline__ void lean_h1(const float* __restrict__ xr,
                                        const float* __restrict__ w1,
                                        const float* __restrict__ b1,
                                        const float* __restrict__ ab1,
                                        float (&h)[64]) {
  float x[6];
#pragma unroll
  for (int c = 0; c < 6; ++c) x[c] = xr[c];
#pragma unroll
  for (int o = 0; o < 64; ++o) {
    float acc = b1[o];
#pragma unroll
    for (int c = 0; c < 6; ++c) acc = fmaf(x[c], w1[o*6+c], acc);
    h[o] = fmaxf(0.f, fmaf(acc, ab1[o], ab1[64+o]));
  }
}

// ---------------------------------------------------------------------------
// Software grid barrier (proven round 2: passed repeatedly). 86KB LDS forces
// 1 block/CU; grid 256 <= 256 CUs -> co-resident -> no deadlock. ACQ_REL RMW
// + ACQUIRE spin gives cross-XCD visibility of all pre-barrier writes.
// ---------------------------------------------------------------------------
__device__ __forceinline__ void gridbar(unsigned* bar, int idx) {
  __syncthreads();
  if (threadIdx.x == 0) {
    __hip_atomic_fetch_add(&bar[idx], 1u, __ATOMIC_ACQ_REL, __HIP_MEMORY_SCOPE_AGENT);
    unsigned v;
    do {
      __builtin_amdgcn_s_sleep(1);
      v = __hip_atomic_load(&bar[idx], __ATOMIC_ACQUIRE, __HIP_MEMORY_SCOPE_AGENT);
    } while (v < 256u);
  }
  __syncthreads();
}

// BN finalize phase (blocks [0,C); 256 threads). Proven double-precision math.
__device__ __forceinline__ void fin_phase(const float* __restrict__ part, int nrows,
                                          int rowstride, int C,
                                          const float* __restrict__ g,
                                          const float* __restrict__ be,
                                          float* __restrict__ ab,
                                          double* ls, double* lq) {
  const int ch = blockIdx.x;
  const int t = threadIdx.x;
  const int qo = rowstride >> 1;
  double s = 0.0, q = 0.0;
  for (int wv = t; wv < nrows; wv += 256) {
    s += (double)part[(size_t)wv*rowstride + ch];
    q += (double)part[(size_t)wv*rowstride + qo + ch];
  }
#pragma unroll
  for (int off = 32; off >= 1; off >>= 1) {
    s += __shfl_down(s, off, 64);
    q += __shfl_down(q, off, 64);
  }
  if ((t & 63) == 0) { ls[t>>6] = s; lq[t>>6] = q; }
  __syncthreads();
  if (t == 0) {
    double S = ls[0]+ls[1]+ls[2]+ls[3];
    double Q = lq[0]+lq[1]+lq[2]+lq[3];
    double mean = S / (double)NR;
    double var  = Q / (double)NR - mean*mean;
    double inv  = 1.0 / sqrt(var + 1e-5);
    double gg   = (double)g[ch];
    ab[ch]     = (float)(gg * inv);
    ab[C + ch] = (float)((double)be[ch] - mean * gg * inv);
  }
}

// ---------------------------------------------------------------------------
// TAIL v2: post-FPS chain in ONE persistent kernel, SPILL-FREE.
//   256 blocks x 256 threads (the proven round-0/1 shape). Register-pressure
//   fix vs round 2 (128-VGPR cap + 750MB scratch traffic): stats2 does a
//   butterfly PER ROW-BATCH (64 rows/wave) and accumulates 2 scalars, so the
//   peak live set is h[64]+z[64] or z[64]+q[64], never 192+. stats3 streams
//   z straight into the LDS tile (no z[64] array).
//   LDS = 86,016B > 80KB -> 1 block/CU -> 256 co-resident blocks (barrier-safe).
// ---------------------------------------------------------------------------
__global__ __launch_bounds__(256, 1) void tail_kernel(
    const float* __restrict__ x0,
    const float* __restrict__ w1, const float* __restrict__ b1,
    const float* __restrict__ g1, const float* __restrict__ be1,
    const float* __restrict__ w2, const float* __restrict__ b2,
    const float* __restrict__ g2, const float* __restrict__ be2,
    const float* __restrict__ w3, const float* __restrict__ b3,
    const float* __restrict__ g3, const float* __restrict__ be3,
    float* __restrict__ part, float* __restrict__ ab,
    unsigned* __restrict__ z2u, float* __restrict__ kmx,
    float* __restrict__ kmn, float* __restrict__ new_points,
    unsigned* __restrict__ bar)
{
  __shared__ double smem[10752];               // 86,016 B (pads to 1 block/CU)
  float* tile = (float*)smem;                  // [256][65] = 66,560B (stats3)
  float* gs   = (float*)smem + 256*65;         // [8][64]
  float* gq   = gs + 8*64;                     // [8][64]
  double* ls  = smem;                          // [4] finalize scratch (aliased)
  double* lq  = smem + 4;                      // [4]

  const int t = threadIdx.x;
  const int lane = t & 63;
  const int wvi = t >> 6;                      // 0..3
  float* ab1 = ab; float* ab2 = ab + 128; float* ab3 = ab + 256;

  // ---- fin1: BN1 stats from per-item partials (16384 x 128) ----
  if (blockIdx.x < 64)
    fin_phase(part, NB*NS, 128, 64, g1, be1, ab1, ls, lq);
  gridbar(bar, 0);

  // ---- stats2: 8 row-batches of 64 rows per wave; butterfly per batch ----
  {
    const int gw2 = (int)blockIdx.x*4 + wvi;   // 0..1023
    float accZ = 0.f, accQ = 0.f;
#pragma unroll 1
    for (int iter = 0; iter < 8; ++iter) {
      const int row = (gw2*8 + iter)*64 + lane;
      float h[64];
      lean_h1(x0 + (size_t)row*6, w1, b1, ab1, h);
      float z[64];
#pragma unroll
      for (int o = 0; o < 64; ++o) {
        float acc = b2[o];
#pragma unroll
        for (int c = 0; c < 64; ++c) acc = fmaf(h[c], w2[o*64+c], acc);
        z[o] = acc;
      }
      uint4* zw = (uint4*)(z2u + (size_t)row * 32);
#pragma unroll
      for (int i = 0; i < 8; ++i)
        zw[i] = make_uint4(pack_bf2(z[8*i+0],z[8*i+1]), pack_bf2(z[8*i+2],z[8*i+3]),
                           pack_bf2(z[8*i+4],z[8*i+5]), pack_bf2(z[8*i+6],z[8*i+7]));
      float q[64];
#pragma unroll
      for (int o = 0; o < 64; ++o) q[o] = z[o]*z[o];
      butterfly64(z, q, lane);
      accZ += z[0]; accQ += q[0];
    }
    const int ch = brev6(lane);
    part[(size_t)gw2*128 + ch]      = accZ;
    part[(size_t)gw2*128 + 64 + ch] = accQ;
  }
  gridbar(bar, 1);

  if (blockIdx.x < 64)
    fin_phase(part, 1024, 128, 64, g2, be2, ab2, ls, lq);
  gridbar(bar, 2);

  // ---- stats3: 8 passes of 256-row tiles; kmax/kmin + BN3 partials ----
  {
    float totS0 = 0.f, totS1 = 0.f, totQ0 = 0.f, totQ1 = 0.f;
#pragma unroll 1
    for (int pass = 0; pass < 8; ++pass) {
      const int row = (int)blockIdx.x*2048 + pass*256 + t;
      const uint4* zr = (const uint4*)(z2u + (size_t)row * 32);
      float h[64];
#pragma unroll
      for (int i = 0; i < 8; ++i) {
        uint4 v = zr[i];
        const int c = i*8;
        h[c+0]=fmaxf(0.f,fmaf(bf_lo(v.x),ab2[c+0],ab2[64+c+0]));
        h[c+1]=fmaxf(0.f,fmaf(bf_hi(v.x),ab2[c+1],ab2[64+c+1]));
        h[c+2]=fmaxf(0.f,fmaf(bf_lo(v.y),ab2[c+2],ab2[64+c+2]));
        h[c+3]=fmaxf(0.f,fmaf(bf_hi(v.y),ab2[c+3],ab2[64+c+3]));
        h[c+4]=fmaxf(0.f,fmaf(bf_lo(v.z),ab2[c+4],ab2[64+c+4]));
        h[c+5]=fmaxf(0.f,fmaf(bf_hi(v.z),ab2[c+5],ab2[64+c+5]));
        h[c+6]=fmaxf(0.f,fmaf(bf_lo(v.w),ab2[c+6],ab2[64+c+6]));
        h[c+7]=fmaxf(0.f,fmaf(bf_hi(v.w),ab2[c+7],ab2[64+c+7]));
      }
#pragma unroll 1
      for (int chunk = 0; chunk < 2; ++chunk) {
        // stream z straight into the tile (no z[64] register array)
#pragma unroll
        for (int o = 0; o < 64; ++o) {
          float acc = b3[chunk*64 + o];
          const float* wr = w3 + (size_t)(chunk*64 + o) * 64;
#pragma unroll
          for (int c = 0; c < 64; ++c) acc = fmaf(h[c], wr[c], acc);
          tile[t*65 + o] = acc;
        }
        __syncthreads();
        // wave wvi reduces groups 2*wvi, 2*wvi+1 (8 groups of 32 rows)
#pragma unroll
        for (int i2 = 0; i2 < 2; ++i2) {
          const int g = wvi*2 + i2;
          float m = -1e30f, n = 1e30f, s = 0.f, q = 0.f;
#pragma unroll
          for (int k = 0; k < 32; ++k) {
            float v = tile[(g*32 + k)*65 + lane];
            m = fmaxf(m, v); n = fminf(n, v); s += v; q = fmaf(v, v, q);
          }
          const size_t group = (size_t)blockIdx.x*64 + pass*8 + g;
          kmx[group*128 + chunk*64 + lane] = m;
          kmn[group*128 + chunk*64 + lane] = n;
          gs[g*64 + lane] = s; gq[g*64 + lane] = q;
        }
        __syncthreads();
        if (t < 128) {
          const int c = t & 63;
          float tot = 0.f;
          if (t < 64) {
#pragma unroll
            for (int g = 0; g < 8; ++g) tot += gs[g*64 + c];
            if (chunk == 0) totS0 += tot; else totS1 += tot;
          } else {
#pragma unroll
            for (int g = 0; g < 8; ++g) tot += gq[g*64 + c];
            if (chunk == 0) totQ0 += tot; else totQ1 += tot;
          }
        }
        __syncthreads();
      }
    }
    // part rows: 256 x 256 -> [sum(c0..63), sum(c64..127), sq(c0..63), sq(c64..127)]
    if (t < 64) {
      part[(size_t)blockIdx.x*256 + t]      = totS0;
      part[(size_t)blockIdx.x*256 + 64 + t] = totS1;
    } else if (t < 128) {
      part[(size_t)blockIdx.x*256 + 128 + (t-64)] = totQ0;
      part[(size_t)blockIdx.x*256 + 192 + (t-64)] = totQ1;
    }
  }
  gridbar(bar, 3);

  if (blockIdx.x < 128)
    fin_phase(part, 256, 256, 128, g3, be3, ab3, ls, lq);
  gridbar(bar, 4);

  // ---- bn3: out = relu(a*sel + b), sel = a>=0 ? kmax : kmin ----
#pragma unroll 1
  for (int k = 0; k < 32; ++k) {
    const size_t idx = (size_t)k*65536 + (size_t)blockIdx.x*256 + t;
    const int c = (int)(idx & 127);
    const float a = ab3[c], bsh = ab3[128 + c];
    const float v = (a >= 0.f) ? kmx[idx] : kmn[idx];
    new_points[idx] = fmaxf(0.f, fmaf(v, a, bsh));
  }
}

// ============================ launcher ============================

extern "C" void kernel_launch(void* const* d_in, const int* in_sizes, int n_in,
                              void* d_out, int out_size, void* d_ws, size_t ws_size,
                              hipStream_t stream) {
  (void)in_sizes; (void)n_in; (void)out_size; (void)ws_size;
  const float* xyz = (const float*)d_in[0];
  const float* pts = (const float*)d_in[1];
  const float* w1  = (const float*)d_in[2];
  const float* b1  = (const float*)d_in[3];
  const float* g1  = (const float*)d_in[4];
  const float* be1 = (const float*)d_in[5];
  const float* w2  = (const float*)d_in[6];
  const float* b2  = (const float*)d_in[7];
  const float* g2  = (const float*)d_in[8];
  const float* be2 = (const float*)d_in[9];
  const float* w3  = (const float*)d_in[10];
  const float* b3  = (const float*)d_in[11];
  const float* g3  = (const float*)d_in[12];
  const float* be3 = (const float*)d_in[13];

  float* out = (float*)d_out;
  float* new_xyz    = out;
  float* new_points = out + NB*NS*3;

  // ws: x0 12.6MB | part 8.4MB | ab 2KB | z2u 67MB | kmx 8MB | kmn 8MB | bar
  float* ws = (float*)d_ws;
  float* x0   = ws;                               // NR*6
  float* part = x0 + (size_t)NR*6;                // 2097152 floats (16384*128)
  float* ab   = part + 2097152;                   // 512
  unsigned* z2u = (unsigned*)(ab + 512);          // NR*32 u32
  float* kmx = (float*)(z2u + (size_t)NR*32);     // 16384*128
  float* kmn = kmx + (size_t)16384*128;           // 16384*128
  unsigned* bar = (unsigned*)(kmn + (size_t)16384*128); // 8 u32 barrier ctrs

  // NaN-poison new_xyz (publish sentinel) + zero barrier counters.
  (void)hipMemsetAsync(new_xyz, 0xFF, (size_t)NB*NS*3*sizeof(float), stream);
  (void)hipMemsetAsync(bar, 0, 8*sizeof(unsigned), stream);

  hipLaunchKernelGGL(fps_bq_s1_kernel, dim3(NFPS + NWORK), dim3(512), 0, stream,
                     xyz, pts, w1, b1, new_xyz, x0, part);

  hipLaunchKernelGGL(tail_kernel, dim3(256), dim3(256), 0, stream,
                     x0, w1, b1, g1, be1, w2, b2, g2, be2, w3, b3, g3, be3,
                     part, ab, z2u, kmx, kmn, new_points, bar);
}

// Round 4
// 1653.036 us; speedup vs baseline: 1.6282x; 1.4868x over previous
//
#include <hip/hip_runtime.h>

#define NB 16
#define NN 8192
#define NS 1024
#define NK 32
#define NR (NB*NS*NK)   // 524288 rows through the MLP

#define NFPS 16          // fps blocks (one per batch)
#define NWORK 240        // persistent worker blocks (ballquery + stats1)
#define NWAVES (NWORK*8) // 1920 worker waves

static __device__ __forceinline__ int brev6(int l) {
  return ((l&1)<<5)|((l&2)<<3)|((l&4)<<1)|((l&8)>>1)|((l&16)>>3)|((l&32)>>5);
}

// pack two f32 -> two bf16 (RNE) in one uint (low = first)
static __device__ __forceinline__ unsigned pack_bf2(float a, float b) {
  unsigned ua = __float_as_uint(a), ub = __float_as_uint(b);
  ua += 0x7fffu + ((ua >> 16) & 1u);
  ub += 0x7fffu + ((ub >> 16) & 1u);
  return (ua >> 16) | (ub & 0xffff0000u);
}
static __device__ __forceinline__ float bf_lo(unsigned u) { return __uint_as_float(u << 16); }
static __device__ __forceinline__ float bf_hi(unsigned u) { return __uint_as_float(u & 0xffff0000u); }

// ---------------------------------------------------------------------------
// FUSED fps + ballquery + stats1 (structure proven at 1109us round 1-3).
// Delta vs round 3: workers accumulate stats1 sums ACROSS their items in
// registers and write ONE part row per wave (1920 x 128 instead of
// 16384 x 128) -> fin1 reads 8.5x less, strided reads mostly gone.
// ---------------------------------------------------------------------------
__global__ __launch_bounds__(512, 1) void fps_bq_s1_kernel(
    const float* __restrict__ xyz, const float* __restrict__ pts,
    const float* __restrict__ w1,  const float* __restrict__ b1,
    float* __restrict__ new_xyz,   float* __restrict__ x0,
    float* __restrict__ part)
{
  __shared__ float sx[NN], sy[NN], sz[NN];
  __shared__ unsigned long long s_wb[2][8];

  if (blockIdx.x < NFPS) {
    // ------------------------- FPS producer (r11-exact, DO NOT TOUCH) ------
    const int b = blockIdx.x;
    const int t = threadIdx.x;
    const int lane = t & 63;
    const int wv = t >> 6;
    const float* base = xyz + (size_t)b * NN * 3;

    float px[16], py[16], pz[16], dist[16];
#pragma unroll
    for (int j = 0; j < 16; ++j) {
      int p = j * 512 + t;
      float x = base[p*3+0], y = base[p*3+1], z = base[p*3+2];
      px[j] = x; py[j] = y; pz[j] = z; dist[j] = 1e10f;
      sx[p] = x; sy[p] = y; sz[p] = z;
    }
    __syncthreads();

    float cx = sx[0], cy = sy[0], cz = sz[0];
    unsigned* outp = (unsigned*)(new_xyz + (size_t)b * NS * 3);
    if (t == 0) {
      __hip_atomic_store(outp+0, __float_as_uint(cx), __ATOMIC_RELAXED, __HIP_MEMORY_SCOPE_AGENT);
      __hip_atomic_store(outp+1, __float_as_uint(cy), __ATOMIC_RELAXED, __HIP_MEMORY_SCOPE_AGENT);
      __hip_atomic_store(outp+2, __float_as_uint(cz), __ATOMIC_RELAXED, __HIP_MEMORY_SCOPE_AGENT);
    }

    for (int s = 1; s < NS; ++s) {
      const int par = s & 1;
      float bestv = -1.0f;
#pragma unroll
      for (int j = 0; j < 16; ++j) {
        float dx = px[j]-cx, dy = py[j]-cy, dz = pz[j]-cz;
        float d = __fadd_rn(__fadd_rn(__fmul_rn(dx,dx),__fmul_rn(dy,dy)),__fmul_rn(dz,dz));
        float nd = fminf(dist[j], d);
        dist[j] = nd;
        bestv = fmaxf(bestv, nd);
      }
      float wmax = bestv;
#pragma unroll
      for (int off = 32; off >= 1; off >>= 1)
        wmax = fmaxf(wmax, __shfl_xor(wmax, off, 64));
      int minj = 0;
#pragma unroll
      for (int j = 15; j >= 0; --j) if (dist[j] == wmax) minj = j;
      const int myidx = minj * 512 + t;
      const unsigned long long mask = __ballot(bestv == wmax);
      int l0 = __ffsll((unsigned long long)mask) - 1;
      int widx = __shfl(myidx, l0, 64);
      if (__popcll(mask) > 1) {
        unsigned long long m = mask & (mask - 1);
        while (m) {
          int l = __ffsll((unsigned long long)m) - 1;
          int v = __shfl(myidx, l, 64);
          widx = min(widx, v);
          m &= m - 1;
        }
      }
      if (lane == 0)
        s_wb[par][wv] = ((unsigned long long)__float_as_uint(wmax) << 32)
                        | (unsigned)(8191 - widx);
      __syncthreads();
      unsigned long long gk = s_wb[par][0];
#pragma unroll
      for (int i = 1; i < 8; ++i) {
        unsigned long long ki = s_wb[par][i]; if (ki > gk) gk = ki;
      }
      const int bi = 8191 - (int)(gk & 0xffffull);
      cx = sx[bi]; cy = sy[bi]; cz = sz[bi];
      if (t == 0) {
        unsigned* o = outp + s*3;
        __hip_atomic_store(o+0, __float_as_uint(cx), __ATOMIC_RELAXED, __HIP_MEMORY_SCOPE_AGENT);
        __hip_atomic_store(o+1, __float_as_uint(cy), __ATOMIC_RELAXED, __HIP_MEMORY_SCOPE_AGENT);
        __hip_atomic_store(o+2, __float_as_uint(cz), __ATOMIC_RELAXED, __HIP_MEMORY_SCOPE_AGENT);
      }
    }
  } else {
    // --------------------- persistent BQ+stats1 workers ---------------------
    const int wid  = ((int)blockIdx.x - NFPS) * 8 + (threadIdx.x >> 6);
    const int lane = threadIdx.x & 63;
    float wrow[6];
#pragma unroll
    for (int c = 0; c < 6; ++c) wrow[c] = w1[lane*6 + c];
    const float bv = b1[lane];
    const float R2 = 0.04f;
    float itemS = 0.f, itemQ = 0.f;   // per-wave accumulated BN1 partials

    for (int item = wid; item < NB*NS; item += NWAVES) {
      const int s = item >> 4;        // s-major: early centroids first
      const int b = item & 15;
      const int gw = (b << 10) + s;
      const float* base  = xyz + (size_t)b * NN * 3;
      const float* pbase = pts + (size_t)b * NN * 3;
      float* out = x0 + (size_t)gw * (NK*6);

      const unsigned* cp = (const unsigned*)(new_xyz + (size_t)gw * 3);
      float cx, cy, cz;
      for (;;) {
        unsigned ux = __hip_atomic_load(cp+0, __ATOMIC_RELAXED, __HIP_MEMORY_SCOPE_AGENT);
        unsigned uy = __hip_atomic_load(cp+1, __ATOMIC_RELAXED, __HIP_MEMORY_SCOPE_AGENT);
        unsigned uz = __hip_atomic_load(cp+2, __ATOMIC_RELAXED, __HIP_MEMORY_SCOPE_AGENT);
        if (ux != 0xFFFFFFFFu && uy != 0xFFFFFFFFu && uz != 0xFFFFFFFFu) {
          cx = __uint_as_float(ux); cy = __uint_as_float(uy); cz = __uint_as_float(uz);
          break;
        }
        __builtin_amdgcn_s_sleep(16);
      }

      // ---- ball query (bit-identical numerics) ----
      const float t1 = __fadd_rn(__fadd_rn(__fmul_rn(cx,cx),__fmul_rn(cy,cy)),__fmul_rn(cz,cz));
      int count = 0, pfirst = 0;
      for (int n0 = 0; n0 < NN; n0 += 64) {
        const int p = n0 + lane;
        const float ax = base[p*3], ay = base[p*3+1], az = base[p*3+2];
        const float t2 = __fadd_rn(__fadd_rn(__fmul_rn(ax,ax),__fmul_rn(ay,ay)),__fmul_rn(az,az));
        const float dt = __fmaf_rn(cz, az, __fmaf_rn(cy, ay, __fmul_rn(cx, ax)));
        const float sq = __fadd_rn(__fsub_rn(t1, __fmul_rn(2.0f,dt)), t2);
        const bool keep = !(sq > R2);
        const unsigned long long mask = __ballot(keep);
        const int slot = count + __popcll(mask & ((1ull<<lane)-1ull));
        if (keep && slot < NK) {
          float* o = out + slot*6;
          o[0]=ax-cx; o[1]=ay-cy; o[2]=az-cz;
          o[3]=pbase[p*3]; o[4]=pbase[p*3+1]; o[5]=pbase[p*3+2];
        }
        if (count == 0 && mask != 0ull) pfirst = n0 + (__ffsll((unsigned long long)mask) - 1);
        count += __popcll(mask);
        if (count >= NK) break;
      }
      if (count < NK) {
        const float* fx = base + (size_t)pfirst*3;
        const float* fp = pbase + (size_t)pfirst*3;
        const float a0 = fx[0]-cx, a1 = fx[1]-cy, a2 = fx[2]-cz;
        const float a3 = fp[0], a4 = fp[1], a5 = fp[2];
        for (int sl = count + lane; sl < NK; sl += 64) {
          float* o = out + sl*6;
          o[0]=a0;o[1]=a1;o[2]=a2;o[3]=a3;o[4]=a4;o[5]=a5;
        }
      }

      // ---- stats1 for this item's 32 rows (lane = channel) ----
      __threadfence_block();
      float sAcc = 0.f, qAcc = 0.f;
#pragma unroll 4
      for (int k = 0; k < NK; ++k) {
        const float* row = out + k*6;
        float z = bv;
#pragma unroll
        for (int c = 0; c < 6; ++c) z = fmaf(row[c], wrow[c], z);
        sAcc += z;
        qAcc = fmaf(z, z, qAcc);
      }
      itemS += sAcc;
      itemQ += qAcc;
    }
    // one part row per wave: [1920][128]
    part[(size_t)wid*128 + lane]      = itemS;
    part[(size_t)wid*128 + 64 + lane] = itemQ;
  }
}

// ---------------------------------------------------------------------------
// butterfly64: z[0] = wave sum of channel brev6(lane).
// ---------------------------------------------------------------------------
__device__ __forceinline__ void butterfly64(float (&z)[64], float (&q)[64], int lane) {
#pragma unroll
  for (int d = 0; d < 6; ++d) {
    const int m = 32 >> d;
    const bool hi = (lane >> d) & 1;
#pragma unroll
    for (int i = 0; i < m; ++i) {
      float sv = hi ? z[i] : z[i+m];
      float rv = __shfl_xor(sv, 1<<d, 64);
      z[i] = (hi ? z[i+m] : z[i]) + rv;
      float sq = hi ? q[i] : q[i+m];
      float rq = __shfl_xor(sq, 1<<d, 64);
      q[i] = (hi ? q[i+m] : q[i]) + rq;
    }
  }
}

// ---------------------------------------------------------------------------
// BN finalize (nrows = partial-row count).
// ---------------------------------------------------------------------------
__global__ __launch_bounds__(256) void finalize_kernel(const float* __restrict__ part,
                                                       int nrows, int rowstride, int C,
                                                       const float* __restrict__ g,
                                                       const float* __restrict__ be,
                                                       float* __restrict__ ab) {
  const int ch = blockIdx.x;
  const int t = threadIdx.x;
  const int qo = rowstride >> 1;
  double s = 0.0, q = 0.0;
  for (int wv = t; wv < nrows; wv += 256) {
    s += (double)part[(size_t)wv*rowstride + ch];
    q += (double)part[(size_t)wv*rowstride + qo + ch];
  }
#pragma unroll
  for (int off = 32; off >= 1; off >>= 1) {
    s += __shfl_down(s, off, 64);
    q += __shfl_down(q, off, 64);
  }
  __shared__ double ls[4], lq[4];
  if ((t & 63) == 0) { ls[t>>6] = s; lq[t>>6] = q; }
  __syncthreads();
  if (t == 0) {
    double S = ls[0]+ls[1]+ls[2]+ls[3];
    double Q = lq[0]+lq[1]+lq[2]+lq[3];
    double mean = S / (double)NR;
    double var  = Q / (double)NR - mean*mean;
    double inv  = 1.0 / sqrt(var + 1e-5);
    double gg   = (double)g[ch];
    ab[ch]     = (float)(gg * inv);
    ab[C + ch] = (float)((double)be[ch] - mean * gg * inv);
  }
}

// ============================ MLP passes ============================

__device__ __forceinline__ void lean_h1(const float* __restrict__ xr,
                                        const float* __restrict__ w1,
                                        const float* __restrict__ b1,
                                        const float* __restrict__ ab1,
                                        float (&h)[64]) {
  float x[6];
#pragma unroll
  for (int c = 0; c < 6; ++c) x[c] = xr[c];
#pragma unroll
  for (int o = 0; o < 64; ++o) {
    float acc = b1[o];
#pragma unroll
    for (int c = 0; c < 6; ++c) acc = fmaf(x[c], w1[o*6+c], acc);
    h[o] = fmaxf(0.f, fmaf(acc, ab1[o], ab1[64+o]));
  }
}

__global__ __launch_bounds__(256) void stats2_store(const float* __restrict__ x0,
                                                    const float* __restrict__ w1,
                                                    const float* __restrict__ b1,
                                                    const float* __restrict__ ab1,
                                                    const float* __restrict__ w2,
                                                    const float* __restrict__ b2,
                                                    unsigned* __restrict__ z2u,
                                                    float* __restrict__ part) {
  const int r = blockIdx.x * 256 + threadIdx.x;
  const int lane = threadIdx.x & 63;
  const int wvi = threadIdx.x >> 6;
  __shared__ float red[4][128];
  float h[64];
  lean_h1(x0 + (size_t)r*6, w1, b1, ab1, h);
  float z[64];
#pragma unroll
  for (int o = 0; o < 64; ++o) {
    float acc = b2[o];
#pragma unroll
    for (int c = 0; c < 64; ++c) acc = fmaf(h[c], w2[o*64+c], acc);
    z[o] = acc;
  }
  uint4* zw = (uint4*)(z2u + (size_t)r * 32);
#pragma unroll
  for (int i = 0; i < 8; ++i)
    zw[i] = make_uint4(pack_bf2(z[8*i+0],z[8*i+1]), pack_bf2(z[8*i+2],z[8*i+3]),
                       pack_bf2(z[8*i+4],z[8*i+5]), pack_bf2(z[8*i+6],z[8*i+7]));
  float q[64];
#pragma unroll
  for (int o = 0; o < 64; ++o) q[o] = z[o]*z[o];
  butterfly64(z, q, lane);
  const int ch = brev6(lane);
  red[wvi][ch]      = z[0];
  red[wvi][64 + ch] = q[0];
  __syncthreads();
  const int t = threadIdx.x;
  if (t < 128)
    part[(size_t)blockIdx.x*128 + t] = red[0][t]+red[1][t]+red[2][t]+red[3][t];
}

// ---------------------------------------------------------------------------
// stats3_fused: read z2 bf16, bn2+relu, layer3 (2 chunks of 64 ch) -> LDS
// tile -> per-group (32 rows) max/min/sum/sumsq in one pass.
// Delta vs rounds 0-3: tile stride 65 -> 68. 65 === 1 (mod 32) makes
// ds_write_b128 16-lane phases hit each bank 4x (4-way conflict, the 9.0e7
// SQ_LDS_BANK_CONFLICT seen in round 3); 68 === 4 (mod 32) gives exactly
// 2 touches/bank = conflict-free. Column reads stay conflict-free.
// LDS 73,728B -> still 2 blocks/CU.
// ---------------------------------------------------------------------------
__global__ __launch_bounds__(256) void stats3_fused(const unsigned* __restrict__ z2u,
                                                    const float* __restrict__ ab,
                                                    const float* __restrict__ w,
                                                    const float* __restrict__ bias,
                                                    float* __restrict__ part,
                                                    float* __restrict__ kmx,
                                                    float* __restrict__ kmn) {
  const int r = blockIdx.x * 256 + threadIdx.x;
  const int t = threadIdx.x;
  const int lane = t & 63;
  const int wvi = t >> 6;                 // 0..3

  __shared__ float tile[256*68];          // 69,632 B
  __shared__ float gs[8][64], gq[8][64];  // per-group partial sum/sumsq

  const uint4* zr = (const uint4*)(z2u + (size_t)r * 32);
  float h[64];
#pragma unroll
  for (int i = 0; i < 8; ++i) {
    uint4 v = zr[i];
    const int c = i*8;
    h[c+0]=fmaxf(0.f,fmaf(bf_lo(v.x),ab[c+0],ab[64+c+0]));
    h[c+1]=fmaxf(0.f,fmaf(bf_hi(v.x),ab[c+1],ab[64+c+1]));
    h[c+2]=fmaxf(0.f,fmaf(bf_lo(v.y),ab[c+2],ab[64+c+2]));
    h[c+3]=fmaxf(0.f,fmaf(bf_hi(v.y),ab[c+3],ab[64+c+3]));
    h[c+4]=fmaxf(0.f,fmaf(bf_lo(v.z),ab[c+4],ab[64+c+4]));
    h[c+5]=fmaxf(0.f,fmaf(bf_hi(v.z),ab[c+5],ab[64+c+5]));
    h[c+6]=fmaxf(0.f,fmaf(bf_lo(v.w),ab[c+6],ab[64+c+6]));
    h[c+7]=fmaxf(0.f,fmaf(bf_hi(v.w),ab[c+7],ab[64+c+7]));
  }

#pragma unroll 1
  for (int chunk = 0; chunk < 2; ++chunk) {
    {
      float z[64];
#pragma unroll
      for (int o = 0; o < 64; ++o) {
        float acc = bias[chunk*64+o];
        const float* wr = w + (size_t)(chunk*64+o) * 64;
#pragma unroll
        for (int c = 0; c < 64; ++c) acc = fmaf(h[c], wr[c], acc);
        z[o] = acc;
      }
#pragma unroll
      for (int o = 0; o < 64; ++o) tile[t*68 + o] = z[o];
    }
    __syncthreads();
    // wave wvi reduces groups 2*wvi and 2*wvi+1; lane owns channel `lane`
#pragma unroll
    for (int i = 0; i < 2; ++i) {
      const int g = wvi*2 + i;
      float m = -1e30f, n = 1e30f, s = 0.f, q = 0.f;
#pragma unroll
      for (int k = 0; k < 32; ++k) {
        float v = tile[(g*32 + k)*68 + lane];
        m = fmaxf(m, v); n = fminf(n, v); s += v; q = fmaf(v, v, q);
      }
      const size_t group = (size_t)blockIdx.x*8 + g;
      kmx[group*128 + chunk*64 + lane] = m;
      kmn[group*128 + chunk*64 + lane] = n;
      gs[g][lane] = s; gq[g][lane] = q;
    }
    __syncthreads();
    if (t < 128) {
      const int c = t & 63;
      float tot = 0.f;
      if (t < 64) {
#pragma unroll
        for (int g = 0; g < 8; ++g) tot += gs[g][c];
        part[(size_t)blockIdx.x*256 + chunk*64 + c] = tot;
      } else {
#pragma unroll
        for (int g = 0; g < 8; ++g) tot += gq[g][c];
        part[(size_t)blockIdx.x*256 + 128 + chunk*64 + c] = tot;
      }
    }
    __syncthreads();
  }
}

// bn3 (r7-validated): out = relu(a*sel + b), sel = a>=0 ? kmax : kmin
__global__ __launch_bounds__(128) void bn3_kernel(const float* __restrict__ kmx,
                                                  const float* __restrict__ kmn,
                                                  const float* __restrict__ ab,
                                                  float* __restrict__ outp) {
  const int g = blockIdx.x;
  const int c = threadIdx.x;
  const float a = ab[c], bsh = ab[128 + c];
  const float v = (a >= 0.f) ? kmx[(size_t)g*128 + c] : kmn[(size_t)g*128 + c];
  outp[(size_t)g*128 + c] = fmaxf(0.f, fmaf(v, a, bsh));
}

// ============================ launcher ============================

extern "C" void kernel_launch(void* const* d_in, const int* in_sizes, int n_in,
                              void* d_out, int out_size, void* d_ws, size_t ws_size,
                              hipStream_t stream) {
  (void)in_sizes; (void)n_in; (void)out_size; (void)ws_size;
  const float* xyz = (const float*)d_in[0];
  const float* pts = (const float*)d_in[1];
  const float* w1  = (const float*)d_in[2];
  const float* b1  = (const float*)d_in[3];
  const float* g1  = (const float*)d_in[4];
  const float* be1 = (const float*)d_in[5];
  const float* w2  = (const float*)d_in[6];
  const float* b2  = (const float*)d_in[7];
  const float* g2  = (const float*)d_in[8];
  const float* be2 = (const float*)d_in[9];
  const float* w3  = (const float*)d_in[10];
  const float* b3  = (const float*)d_in[11];
  const float* g3  = (const float*)d_in[12];
  const float* be3 = (const float*)d_in[13];

  float* out = (float*)d_out;
  float* new_xyz    = out;
  float* new_points = out + NB*NS*3;

  // ws: x0 12.6MB | part 8.4MB | ab 2KB | z2u 67MB | kmx 8MB | kmn 8MB ~ 104MB
  float* ws = (float*)d_ws;
  float* x0   = ws;                               // NR*6
  float* part = x0 + (size_t)NR*6;                // up to 2048*256 floats
  float* ab   = part + 2097152;                   // 512
  float* ab1  = ab;
  float* ab2  = ab + 128;
  float* ab3  = ab + 256;
  unsigned* z2u = (unsigned*)(ab + 512);          // NR*32 u32
  float* kmx = (float*)(z2u + (size_t)NR*32);     // 16384*128
  float* kmn = kmx + (size_t)16384*128;           // 16384*128
  const int NBLK = NR/256;                        // 2048

  // NaN-poison new_xyz: the fused kernel's publish sentinel.
  (void)hipMemsetAsync(new_xyz, 0xFF, (size_t)NB*NS*3*sizeof(float), stream);

  // fused FPS (blocks 0..15) + persistent ballquery/stats1 workers (16..255);
  // part written per-WAVE: [1920][128] (sum | sumsq)
  hipLaunchKernelGGL(fps_bq_s1_kernel, dim3(NFPS + NWORK), dim3(512), 0, stream,
                     xyz, pts, w1, b1, new_xyz, x0, part);

  hipLaunchKernelGGL(finalize_kernel, dim3(64), dim3(256), 0, stream, part, NWAVES, 128, 64, g1, be1, ab1);
  hipLaunchKernelGGL(stats2_store, dim3(NBLK), dim3(256), 0, stream,
                     x0, w1, b1, ab1, w2, b2, z2u, part);
  hipLaunchKernelGGL(finalize_kernel, dim3(64), dim3(256), 0, stream, part, NBLK, 128, 64, g2, be2, ab2);
  hipLaunchKernelGGL(stats3_fused, dim3(NBLK), dim3(256), 0, stream,
                     z2u, ab2, w3, b3, part, kmx, kmn);
  hipLaunchKernelGGL(finalize_kernel, dim3(128), dim3(256), 0, stream, part, NBLK, 256, 128, g3, be3, ab3);
  hipLaunchKernelGGL(bn3_kernel, dim3(NB*NS), dim3(128), 0, stream, kmx, kmn, ab3, new_points);
}

// Round 5
// 1447.215 us; speedup vs baseline: 1.8598x; 1.1422x over previous
//
#include <hip/hip_runtime.h>

#define NB 16
#define NN 8192
#define NS 1024
#define NK 32
#define NR (NB*NS*NK)   // 524288 rows through the MLP

#define NFPS 16          // fps blocks (one per batch)
#define NWORK 240        // persistent worker blocks (ballquery + stats1)
#define NWAVES (NWORK*8) // 1920 worker waves

static __device__ __forceinline__ int brev6(int l) {
  return ((l&1)<<5)|((l&2)<<3)|((l&4)<<1)|((l&8)>>1)|((l&16)>>3)|((l&32)>>5);
}

// pack two f32 -> two bf16 (RNE) in one uint (low = first)
static __device__ __forceinline__ unsigned pack_bf2(float a, float b) {
  unsigned ua = __float_as_uint(a), ub = __float_as_uint(b);
  ua += 0x7fffu + ((ua >> 16) & 1u);
  ub += 0x7fffu + ((ub >> 16) & 1u);
  return (ua >> 16) | (ub & 0xffff0000u);
}
static __device__ __forceinline__ float bf_lo(unsigned u) { return __uint_as_float(u << 16); }
static __device__ __forceinline__ float bf_hi(unsigned u) { return __uint_as_float(u & 0xffff0000u); }

// ---------------------------------------------------------------------------
// FUSED fps + ballquery + stats1 (UNCHANGED from round 4 — 1120us, passes).
// ---------------------------------------------------------------------------
__global__ __launch_bounds__(512, 1) void fps_bq_s1_kernel(
    const float* __restrict__ xyz, const float* __restrict__ pts,
    const float* __restrict__ w1,  const float* __restrict__ b1,
    float* __restrict__ new_xyz,   float* __restrict__ x0,
    float* __restrict__ part)
{
  __shared__ float sx[NN], sy[NN], sz[NN];
  __shared__ unsigned long long s_wb[2][8];

  if (blockIdx.x < NFPS) {
    // ------------------------- FPS producer (r11-exact, DO NOT TOUCH) ------
    const int b = blockIdx.x;
    const int t = threadIdx.x;
    const int lane = t & 63;
    const int wv = t >> 6;
    const float* base = xyz + (size_t)b * NN * 3;

    float px[16], py[16], pz[16], dist[16];
#pragma unroll
    for (int j = 0; j < 16; ++j) {
      int p = j * 512 + t;
      float x = base[p*3+0], y = base[p*3+1], z = base[p*3+2];
      px[j] = x; py[j] = y; pz[j] = z; dist[j] = 1e10f;
      sx[p] = x; sy[p] = y; sz[p] = z;
    }
    __syncthreads();

    float cx = sx[0], cy = sy[0], cz = sz[0];
    unsigned* outp = (unsigned*)(new_xyz + (size_t)b * NS * 3);
    if (t == 0) {
      __hip_atomic_store(outp+0, __float_as_uint(cx), __ATOMIC_RELAXED, __HIP_MEMORY_SCOPE_AGENT);
      __hip_atomic_store(outp+1, __float_as_uint(cy), __ATOMIC_RELAXED, __HIP_MEMORY_SCOPE_AGENT);
      __hip_atomic_store(outp+2, __float_as_uint(cz), __ATOMIC_RELAXED, __HIP_MEMORY_SCOPE_AGENT);
    }

    for (int s = 1; s < NS; ++s) {
      const int par = s & 1;
      float bestv = -1.0f;
#pragma unroll
      for (int j = 0; j < 16; ++j) {
        float dx = px[j]-cx, dy = py[j]-cy, dz = pz[j]-cz;
        float d = __fadd_rn(__fadd_rn(__fmul_rn(dx,dx),__fmul_rn(dy,dy)),__fmul_rn(dz,dz));
        float nd = fminf(dist[j], d);
        dist[j] = nd;
        bestv = fmaxf(bestv, nd);
      }
      float wmax = bestv;
#pragma unroll
      for (int off = 32; off >= 1; off >>= 1)
        wmax = fmaxf(wmax, __shfl_xor(wmax, off, 64));
      int minj = 0;
#pragma unroll
      for (int j = 15; j >= 0; --j) if (dist[j] == wmax) minj = j;
      const int myidx = minj * 512 + t;
      const unsigned long long mask = __ballot(bestv == wmax);
      int l0 = __ffsll((unsigned long long)mask) - 1;
      int widx = __shfl(myidx, l0, 64);
      if (__popcll(mask) > 1) {
        unsigned long long m = mask & (mask - 1);
        while (m) {
          int l = __ffsll((unsigned long long)m) - 1;
          int v = __shfl(myidx, l, 64);
          widx = min(widx, v);
          m &= m - 1;
        }
      }
      if (lane == 0)
        s_wb[par][wv] = ((unsigned long long)__float_as_uint(wmax) << 32)
                        | (unsigned)(8191 - widx);
      __syncthreads();
      unsigned long long gk = s_wb[par][0];
#pragma unroll
      for (int i = 1; i < 8; ++i) {
        unsigned long long ki = s_wb[par][i]; if (ki > gk) gk = ki;
      }
      const int bi = 8191 - (int)(gk & 0xffffull);
      cx = sx[bi]; cy = sy[bi]; cz = sz[bi];
      if (t == 0) {
        unsigned* o = outp + s*3;
        __hip_atomic_store(o+0, __float_as_uint(cx), __ATOMIC_RELAXED, __HIP_MEMORY_SCOPE_AGENT);
        __hip_atomic_store(o+1, __float_as_uint(cy), __ATOMIC_RELAXED, __HIP_MEMORY_SCOPE_AGENT);
        __hip_atomic_store(o+2, __float_as_uint(cz), __ATOMIC_RELAXED, __HIP_MEMORY_SCOPE_AGENT);
      }
    }
  } else {
    // --------------------- persistent BQ+stats1 workers ---------------------
    const int wid  = ((int)blockIdx.x - NFPS) * 8 + (threadIdx.x >> 6);
    const int lane = threadIdx.x & 63;
    float wrow[6];
#pragma unroll
    for (int c = 0; c < 6; ++c) wrow[c] = w1[lane*6 + c];
    const float bv = b1[lane];
    const float R2 = 0.04f;
    float itemS = 0.f, itemQ = 0.f;   // per-wave accumulated BN1 partials

    for (int item = wid; item < NB*NS; item += NWAVES) {
      const int s = item >> 4;        // s-major: early centroids first
      const int b = item & 15;
      const int gw = (b << 10) + s;
      const float* base  = xyz + (size_t)b * NN * 3;
      const float* pbase = pts + (size_t)b * NN * 3;
      float* out = x0 + (size_t)gw * (NK*6);

      const unsigned* cp = (const unsigned*)(new_xyz + (size_t)gw * 3);
      float cx, cy, cz;
      for (;;) {
        unsigned ux = __hip_atomic_load(cp+0, __ATOMIC_RELAXED, __HIP_MEMORY_SCOPE_AGENT);
        unsigned uy = __hip_atomic_load(cp+1, __ATOMIC_RELAXED, __HIP_MEMORY_SCOPE_AGENT);
        unsigned uz = __hip_atomic_load(cp+2, __ATOMIC_RELAXED, __HIP_MEMORY_SCOPE_AGENT);
        if (ux != 0xFFFFFFFFu && uy != 0xFFFFFFFFu && uz != 0xFFFFFFFFu) {
          cx = __uint_as_float(ux); cy = __uint_as_float(uy); cz = __uint_as_float(uz);
          break;
        }
        __builtin_amdgcn_s_sleep(16);
      }

      // ---- ball query (bit-identical numerics) ----
      const float t1 = __fadd_rn(__fadd_rn(__fmul_rn(cx,cx),__fmul_rn(cy,cy)),__fmul_rn(cz,cz));
      int count = 0, pfirst = 0;
      for (int n0 = 0; n0 < NN; n0 += 64) {
        const int p = n0 + lane;
        const float ax = base[p*3], ay = base[p*3+1], az = base[p*3+2];
        const float t2 = __fadd_rn(__fadd_rn(__fmul_rn(ax,ax),__fmul_rn(ay,ay)),__fmul_rn(az,az));
        const float dt = __fmaf_rn(cz, az, __fmaf_rn(cy, ay, __fmul_rn(cx, ax)));
        const float sq = __fadd_rn(__fsub_rn(t1, __fmul_rn(2.0f,dt)), t2);
        const bool keep = !(sq > R2);
        const unsigned long long mask = __ballot(keep);
        const int slot = count + __popcll(mask & ((1ull<<lane)-1ull));
        if (keep && slot < NK) {
          float* o = out + slot*6;
          o[0]=ax-cx; o[1]=ay-cy; o[2]=az-cz;
          o[3]=pbase[p*3]; o[4]=pbase[p*3+1]; o[5]=pbase[p*3+2];
        }
        if (count == 0 && mask != 0ull) pfirst = n0 + (__ffsll((unsigned long long)mask) - 1);
        count += __popcll(mask);
        if (count >= NK) break;
      }
      if (count < NK) {
        const float* fx = base + (size_t)pfirst*3;
        const float* fp = pbase + (size_t)pfirst*3;
        const float a0 = fx[0]-cx, a1 = fx[1]-cy, a2 = fx[2]-cz;
        const float a3 = fp[0], a4 = fp[1], a5 = fp[2];
        for (int sl = count + lane; sl < NK; sl += 64) {
          float* o = out + sl*6;
          o[0]=a0;o[1]=a1;o[2]=a2;o[3]=a3;o[4]=a4;o[5]=a5;
        }
      }

      // ---- stats1 for this item's 32 rows (lane = channel) ----
      __threadfence_block();
      float sAcc = 0.f, qAcc = 0.f;
#pragma unroll 4
      for (int k = 0; k < NK; ++k) {
        const float* row = out + k*6;
        float z = bv;
#pragma unroll
        for (int c = 0; c < 6; ++c) z = fmaf(row[c], wrow[c], z);
        sAcc += z;
        qAcc = fmaf(z, z, qAcc);
      }
      itemS += sAcc;
      itemQ += qAcc;
    }
    // one part row per wave: [1920][128]
    part[(size_t)wid*128 + lane]      = itemS;
    part[(size_t)wid*128 + 64 + lane] = itemQ;
  }
}

// ---------------------------------------------------------------------------
// BN finalize (nrows = partial-row count).
// ---------------------------------------------------------------------------
__global__ __launch_bounds__(256) void finalize_kernel(const float* __restrict__ part,
                                                       int nrows, int rowstride, int C,
                                                       const float* __restrict__ g,
                                                       const float* __restrict__ be,
                                                       float* __restrict__ ab) {
  const int ch = blockIdx.x;
  const int t = threadIdx.x;
  const int qo = rowstride >> 1;
  double s = 0.0, q = 0.0;
  for (int wv = t; wv < nrows; wv += 256) {
    s += (double)part[(size_t)wv*rowstride + ch];
    q += (double)part[(size_t)wv*rowstride + qo + ch];
  }
#pragma unroll
  for (int off = 32; off >= 1; off >>= 1) {
    s += __shfl_down(s, off, 64);
    q += __shfl_down(q, off, 64);
  }
  __shared__ double ls[4], lq[4];
  if ((t & 63) == 0) { ls[t>>6] = s; lq[t>>6] = q; }
  __syncthreads();
  if (t == 0) {
    double S = ls[0]+ls[1]+ls[2]+ls[3];
    double Q = lq[0]+lq[1]+lq[2]+lq[3];
    double mean = S / (double)NR;
    double var  = Q / (double)NR - mean*mean;
    double inv  = 1.0 / sqrt(var + 1e-5);
    double gg   = (double)g[ch];
    ab[ch]     = (float)(gg * inv);
    ab[C + ch] = (float)((double)be[ch] - mean * gg * inv);
  }
}

// ============================ MLP passes ============================

__device__ __forceinline__ void lean_h1(const float* __restrict__ xr,
                                        const float* __restrict__ w1,
                                        const float* __restrict__ b1,
                                        const float* __restrict__ ab1,
                                        float (&h)[64]) {
  float x[6];
#pragma unroll
  for (int c = 0; c < 6; ++c) x[c] = xr[c];
#pragma unroll
  for (int o = 0; o < 64; ++o) {
    float acc = b1[o];
#pragma unroll
    for (int c = 0; c < 6; ++c) acc = fmaf(x[c], w1[o*6+c], acc);
    h[o] = fmaxf(0.f, fmaf(acc, ab1[o], ab1[64+o]));
  }
}

// ---------------------------------------------------------------------------
// stats2 v2: lane = OUTPUT channel, w2 row register-resident (zero weight
// loads in the GEMM loop). Per wave: 64 rows end-to-end, no cross-wave sync.
//   phase A (lane=row): lean_h1 -> per-wave LDS h-tile (stride 68, f4-aligned)
//   phase B (lane=o):   z[r][o] via 16 broadcast ds_read_b128 + 64 fma/row
//                       (8 fma per LDS read), z2u bf16 store via lane-pair
//                       shfl, channel sums in 2 scalar regs (butterfly gone).
// fma order per row identical to round 4 (c ascending) -> bit-identical z2.
// LDS 71,680B -> 2 blocks/CU.
// ---------------------------------------------------------------------------
__global__ __launch_bounds__(256) void stats2_store(const float* __restrict__ x0,
                                                    const float* __restrict__ w1,
                                                    const float* __restrict__ b1,
                                                    const float* __restrict__ ab1,
                                                    const float* __restrict__ w2,
                                                    const float* __restrict__ b2,
                                                    unsigned* __restrict__ z2u,
                                                    float* __restrict__ part) {
  const int t = threadIdx.x;
  const int lane = t & 63;
  const int wvi = t >> 6;
  __shared__ float hT[4][64*68];       // 69,632 B
  __shared__ float rS[4][64], rQ[4][64];

  const int row0 = ((int)blockIdx.x*4 + wvi) * 64;
  float* ht = hT[wvi];

  // ---- phase A: lane = row ----
  {
    float h[64];
    lean_h1(x0 + (size_t)(row0 + lane)*6, w1, b1, ab1, h);
    float4* hw = (float4*)(ht + lane*68);
#pragma unroll
    for (int c4 = 0; c4 < 16; ++c4)
      hw[c4] = make_float4(h[4*c4+0], h[4*c4+1], h[4*c4+2], h[4*c4+3]);
  }
  asm volatile("s_waitcnt lgkmcnt(0)" ::: "memory");

  // ---- phase B: lane = output channel o ----
  float w2r[64];
  {
    const float4* wr = (const float4*)(w2 + (size_t)lane*64);
#pragma unroll
    for (int c4 = 0; c4 < 16; ++c4) {
      float4 v = wr[c4];
      w2r[4*c4+0]=v.x; w2r[4*c4+1]=v.y; w2r[4*c4+2]=v.z; w2r[4*c4+3]=v.w;
    }
  }
  const float bz = b2[lane];
  float accS = 0.f, accQ = 0.f;
#pragma unroll 2
  for (int r = 0; r < 64; ++r) {
    const float4* hr = (const float4*)(ht + r*68);
    float z = bz;
#pragma unroll
    for (int c4 = 0; c4 < 16; ++c4) {
      float4 hv = hr[c4];                 // uniform-address broadcast
      z = fmaf(hv.x, w2r[4*c4+0], z);
      z = fmaf(hv.y, w2r[4*c4+1], z);
      z = fmaf(hv.z, w2r[4*c4+2], z);
      z = fmaf(hv.w, w2r[4*c4+3], z);
    }
    accS += z; accQ = fmaf(z, z, accQ);
    const float zp = __shfl_xor(z, 1, 64);
    const unsigned word = (lane & 1) ? pack_bf2(zp, z) : pack_bf2(z, zp);
    if ((lane & 1) == 0)
      z2u[(size_t)(row0 + r)*32 + (lane >> 1)] = word;
  }
  rS[wvi][lane] = accS; rQ[wvi][lane] = accQ;
  __syncthreads();
  if (t < 64)
    part[(size_t)blockIdx.x*128 + t] = rS[0][t]+rS[1][t]+rS[2][t]+rS[3][t];
  else if (t < 128) {
    const int c = t - 64;
    part[(size_t)blockIdx.x*128 + 64 + c] = rQ[0][c]+rQ[1][c]+rQ[2][c]+rQ[3][c];
  }
}

// ---------------------------------------------------------------------------
// stats3 v2: same transposed scheme. lane holds w3 rows o=lane AND o=lane+64
// (128 VGPR, loaded once). Per wave 64 rows = 2 pool-groups of 32; group
// max/min/sum/sumsq accumulate in registers -> tile/gs/gq machinery and all
// per-chunk barriers deleted. kmx/kmn layout unchanged.
// LDS 73,728B -> 2 blocks/CU.
// ---------------------------------------------------------------------------
__global__ __launch_bounds__(256) void stats3_fused(const unsigned* __restrict__ z2u,
                                                    const float* __restrict__ ab,
                                                    const float* __restrict__ w,
                                                    const float* __restrict__ bias,
                                                    float* __restrict__ part,
                                                    float* __restrict__ kmx,
                                                    float* __restrict__ kmn) {
  const int t = threadIdx.x;
  const int lane = t & 63;
  const int wvi = t >> 6;
  __shared__ float hT[4][64*68];       // 69,632 B
  __shared__ float rS[4][128], rQ[4][128];

  const int row0 = ((int)blockIdx.x*4 + wvi) * 64;
  float* ht = hT[wvi];

  // ---- phase A: lane = row; bn2+relu unpack (identical math to round 4) ----
  {
    const uint4* zr = (const uint4*)(z2u + (size_t)(row0 + lane) * 32);
    float h[64];
#pragma unroll
    for (int i = 0; i < 8; ++i) {
      uint4 v = zr[i];
      const int c = i*8;
      h[c+0]=fmaxf(0.f,fmaf(bf_lo(v.x),ab[c+0],ab[64+c+0]));
      h[c+1]=fmaxf(0.f,fmaf(bf_hi(v.x),ab[c+1],ab[64+c+1]));
      h[c+2]=fmaxf(0.f,fmaf(bf_lo(v.y),ab[c+2],ab[64+c+2]));
      h[c+3]=fmaxf(0.f,fmaf(bf_hi(v.y),ab[c+3],ab[64+c+3]));
      h[c+4]=fmaxf(0.f,fmaf(bf_lo(v.z),ab[c+4],ab[64+c+4]));
      h[c+5]=fmaxf(0.f,fmaf(bf_hi(v.z),ab[c+5],ab[64+c+5]));
      h[c+6]=fmaxf(0.f,fmaf(bf_lo(v.w),ab[c+6],ab[64+c+6]));
      h[c+7]=fmaxf(0.f,fmaf(bf_hi(v.w),ab[c+7],ab[64+c+7]));
    }
    float4* hw = (float4*)(ht + lane*68);
#pragma unroll
    for (int c4 = 0; c4 < 16; ++c4)
      hw[c4] = make_float4(h[4*c4+0], h[4*c4+1], h[4*c4+2], h[4*c4+3]);
  }
  asm volatile("s_waitcnt lgkmcnt(0)" ::: "memory");

  // ---- phase B: lane = output channel; chunks o=lane, o=lane+64 ----
  float w3a[64], w3b[64];
  {
    const float4* wra = (const float4*)(w + (size_t)lane*64);
    const float4* wrb = (const float4*)(w + (size_t)(lane+64)*64);
#pragma unroll
    for (int c4 = 0; c4 < 16; ++c4) {
      float4 va = wra[c4];
      w3a[4*c4+0]=va.x; w3a[4*c4+1]=va.y; w3a[4*c4+2]=va.z; w3a[4*c4+3]=va.w;
      float4 vb = wrb[c4];
      w3b[4*c4+0]=vb.x; w3b[4*c4+1]=vb.y; w3b[4*c4+2]=vb.z; w3b[4*c4+3]=vb.w;
    }
  }
  const float bza = bias[lane], bzb = bias[64+lane];
  float sA = 0.f, qA = 0.f, sB = 0.f, qB = 0.f;
#pragma unroll 1
  for (int g2 = 0; g2 < 2; ++g2) {
    float mA = -1e30f, nA = 1e30f, mB = -1e30f, nB = 1e30f;
#pragma unroll 2
    for (int r = g2*32; r < g2*32 + 32; ++r) {
      const float4* hr = (const float4*)(ht + r*68);
      float za = bza, zb = bzb;
#pragma unroll
      for (int c4 = 0; c4 < 16; ++c4) {
        float4 hv = hr[c4];               // uniform-address broadcast
        za = fmaf(hv.x, w3a[4*c4+0], za);
        za = fmaf(hv.y, w3a[4*c4+1], za);
        za = fmaf(hv.z, w3a[4*c4+2], za);
        za = fmaf(hv.w, w3a[4*c4+3], za);
        zb = fmaf(hv.x, w3b[4*c4+0], zb);
        zb = fmaf(hv.y, w3b[4*c4+1], zb);
        zb = fmaf(hv.z, w3b[4*c4+2], zb);
        zb = fmaf(hv.w, w3b[4*c4+3], zb);
      }
      mA = fmaxf(mA, za); nA = fminf(nA, za); sA += za; qA = fmaf(za, za, qA);
      mB = fmaxf(mB, zb); nB = fminf(nB, zb); sB += zb; qB = fmaf(zb, zb, qB);
    }
    const size_t group = (size_t)(((int)blockIdx.x*4 + wvi)*2 + g2);
    kmx[group*128 + lane]      = mA;
    kmx[group*128 + 64 + lane] = mB;
    kmn[group*128 + lane]      = nA;
    kmn[group*128 + 64 + lane] = nB;
  }
  rS[wvi][lane] = sA; rS[wvi][64+lane] = sB;
  rQ[wvi][lane] = qA; rQ[wvi][64+lane] = qB;
  __syncthreads();
  if (t < 128)
    part[(size_t)blockIdx.x*256 + t] = rS[0][t]+rS[1][t]+rS[2][t]+rS[3][t];
  else {
    const int c = t - 128;
    part[(size_t)blockIdx.x*256 + 128 + c] = rQ[0][c]+rQ[1][c]+rQ[2][c]+rQ[3][c];
  }
}

// bn3 (r7-validated): out = relu(a*sel + b), sel = a>=0 ? kmax : kmin
__global__ __launch_bounds__(128) void bn3_kernel(const float* __restrict__ kmx,
                                                  const float* __restrict__ kmn,
                                                  const float* __restrict__ ab,
                                                  float* __restrict__ outp) {
  const int g = blockIdx.x;
  const int c = threadIdx.x;
  const float a = ab[c], bsh = ab[128 + c];
  const float v = (a >= 0.f) ? kmx[(size_t)g*128 + c] : kmn[(size_t)g*128 + c];
  outp[(size_t)g*128 + c] = fmaxf(0.f, fmaf(v, a, bsh));
}

// ============================ launcher ============================

extern "C" void kernel_launch(void* const* d_in, const int* in_sizes, int n_in,
                              void* d_out, int out_size, void* d_ws, size_t ws_size,
                              hipStream_t stream) {
  (void)in_sizes; (void)n_in; (void)out_size; (void)ws_size;
  const float* xyz = (const float*)d_in[0];
  const float* pts = (const float*)d_in[1];
  const float* w1  = (const float*)d_in[2];
  const float* b1  = (const float*)d_in[3];
  const float* g1  = (const float*)d_in[4];
  const float* be1 = (const float*)d_in[5];
  const float* w2  = (const float*)d_in[6];
  const float* b2  = (const float*)d_in[7];
  const float* g2  = (const float*)d_in[8];
  const float* be2 = (const float*)d_in[9];
  const float* w3  = (const float*)d_in[10];
  const float* b3  = (const float*)d_in[11];
  const float* g3  = (const float*)d_in[12];
  const float* be3 = (const float*)d_in[13];

  float* out = (float*)d_out;
  float* new_xyz    = out;
  float* new_points = out + NB*NS*3;

  // ws: x0 12.6MB | part 8.4MB | ab 2KB | z2u 67MB | kmx 8MB | kmn 8MB ~ 104MB
  float* ws = (float*)d_ws;
  float* x0   = ws;                               // NR*6
  float* part = x0 + (size_t)NR*6;                // up to 2048*256 floats
  float* ab   = part + 2097152;                   // 512
  float* ab1  = ab;
  float* ab2  = ab + 128;
  float* ab3  = ab + 256;
  unsigned* z2u = (unsigned*)(ab + 512);          // NR*32 u32
  float* kmx = (float*)(z2u + (size_t)NR*32);     // 16384*128
  float* kmn = kmx + (size_t)16384*128;           // 16384*128
  const int NBLK = NR/256;                        // 2048

  // NaN-poison new_xyz: the fused kernel's publish sentinel.
  (void)hipMemsetAsync(new_xyz, 0xFF, (size_t)NB*NS*3*sizeof(float), stream);

  // fused FPS (blocks 0..15) + persistent ballquery/stats1 workers (16..255);
  // part written per-WAVE: [1920][128] (sum | sumsq)
  hipLaunchKernelGGL(fps_bq_s1_kernel, dim3(NFPS + NWORK), dim3(512), 0, stream,
                     xyz, pts, w1, b1, new_xyz, x0, part);

  hipLaunchKernelGGL(finalize_kernel, dim3(64), dim3(256), 0, stream, part, NWAVES, 128, 64, g1, be1, ab1);
  hipLaunchKernelGGL(stats2_store, dim3(NBLK), dim3(256), 0, stream,
                     x0, w1, b1, ab1, w2, b2, z2u, part);
  hipLaunchKernelGGL(finalize_kernel, dim3(64), dim3(256), 0, stream, part, NBLK, 128, 64, g2, be2, ab2);
  hipLaunchKernelGGL(stats3_fused, dim3(NBLK), dim3(256), 0, stream,
                     z2u, ab2, w3, b3, part, kmx, kmn);
  hipLaunchKernelGGL(finalize_kernel, dim3(128), dim3(256), 0, stream, part, NBLK, 256, 128, g3, be3, ab3);
  hipLaunchKernelGGL(bn3_kernel, dim3(NB*NS), dim3(128), 0, stream, kmx, kmn, ab3, new_points);
}

// Round 6
// 1308.168 us; speedup vs baseline: 2.0575x; 1.1063x over previous
//
#include <hip/hip_runtime.h>

#define NB 16
#define NN 8192
#define NS 1024
#define NK 32
#define NR (NB*NS*NK)   // 524288 rows through the MLP

#define NFPS 16          // fps blocks (one per batch)
#define NWORK 240        // persistent worker blocks (ballquery + stats1)
#define NWAVES (NWORK*8) // 1920 worker waves

static __device__ __forceinline__ int brev6(int l) {
  return ((l&1)<<5)|((l&2)<<3)|((l&4)<<1)|((l&8)>>1)|((l&16)>>3)|((l&32)>>5);
}

// pack two f32 -> two bf16 (RNE) in one uint (low = first)
static __device__ __forceinline__ unsigned pack_bf2(float a, float b) {
  unsigned ua = __float_as_uint(a), ub = __float_as_uint(b);
  ua += 0x7fffu + ((ua >> 16) & 1u);
  ub += 0x7fffu + ((ub >> 16) & 1u);
  return (ua >> 16) | (ub & 0xffff0000u);
}
static __device__ __forceinline__ float bf_lo(unsigned u) { return __uint_as_float(u << 16); }
static __device__ __forceinline__ float bf_hi(unsigned u) { return __uint_as_float(u & 0xffff0000u); }

// ---- DPP wave-64 reductions (VALU pipe, replaces LDS-pipe shuffles) ----
// row_shr:1/2/4/8 -> per-16-row max; row_bcast15 -> lane31=max(0..31),
// lane63=max(32..63); row_bcast31 -> lane63 = full-wave max. bound_ctrl=1
// zero-fills invalid source lanes: harmless for max of values >= 0.
template<int CTRL>
static __device__ __forceinline__ float dppmaxf(float v) {
  int m = __builtin_amdgcn_update_dpp(0, __float_as_int(v), CTRL, 0xf, 0xf, true);
  return fmaxf(v, __int_as_float(m));
}
template<int CTRL>
static __device__ __forceinline__ unsigned dppmaxu(unsigned v) {
  unsigned m = (unsigned)__builtin_amdgcn_update_dpp(0, (int)v, CTRL, 0xf, 0xf, true);
  return v > m ? v : m;
}

// ---------------------------------------------------------------------------
// FUSED fps + ballquery + stats1.
// Round-6 delta (FPS reduction tail only — all FP decision VALUES bit-exact):
//  * wave max via 6 DPP v_max (order-independent max) instead of 6 __shfl_xor
//    (ds_swizzle/bpermute, LDS pipe, serially chained).
//  * per-thread argmax index tracked IN the dist loop (strict >, keeps
//    smallest j at the max == old downward rescan).
//  * min-index-among-matches via DPP u32 max on enc=8191-idx (0 for
//    non-matching lanes) — replaces ballot/ffs/shfl/popcount loop.
//    Produces the EXACT same 64-bit s_wb key as before.
// Cross-wave LDS scan, publishes, workers: unchanged (proven 1120us path).
// ---------------------------------------------------------------------------
__global__ __launch_bounds__(512, 1) void fps_bq_s1_kernel(
    const float* __restrict__ xyz, const float* __restrict__ pts,
    const float* __restrict__ w1,  const float* __restrict__ b1,
    float* __restrict__ new_xyz,   float* __restrict__ x0,
    float* __restrict__ part)
{
  __shared__ float sx[NN], sy[NN], sz[NN];
  __shared__ unsigned long long s_wb[2][8];

  if (blockIdx.x < NFPS) {
    // ------------------------- FPS producer -------------------------
    const int b = blockIdx.x;
    const int t = threadIdx.x;
    const int lane = t & 63;
    const int wv = t >> 6;
    const float* base = xyz + (size_t)b * NN * 3;

    float px[16], py[16], pz[16], dist[16];
#pragma unroll
    for (int j = 0; j < 16; ++j) {
      int p = j * 512 + t;
      float x = base[p*3+0], y = base[p*3+1], z = base[p*3+2];
      px[j] = x; py[j] = y; pz[j] = z; dist[j] = 1e10f;
      sx[p] = x; sy[p] = y; sz[p] = z;
    }
    __syncthreads();

    float cx = sx[0], cy = sy[0], cz = sz[0];
    unsigned* outp = (unsigned*)(new_xyz + (size_t)b * NS * 3);
    if (t == 0) {
      __hip_atomic_store(outp+0, __float_as_uint(cx), __ATOMIC_RELAXED, __HIP_MEMORY_SCOPE_AGENT);
      __hip_atomic_store(outp+1, __float_as_uint(cy), __ATOMIC_RELAXED, __HIP_MEMORY_SCOPE_AGENT);
      __hip_atomic_store(outp+2, __float_as_uint(cz), __ATOMIC_RELAXED, __HIP_MEMORY_SCOPE_AGENT);
    }

    for (int s = 1; s < NS; ++s) {
      const int par = s & 1;
      float bestv = -1.0f;
      int bj = 0;
#pragma unroll
      for (int j = 0; j < 16; ++j) {
        float dx = px[j]-cx, dy = py[j]-cy, dz = pz[j]-cz;
        float d = __fadd_rn(__fadd_rn(__fmul_rn(dx,dx),__fmul_rn(dy,dy)),__fmul_rn(dz,dz));
        float nd = fminf(dist[j], d);
        dist[j] = nd;
        if (nd > bestv) { bestv = nd; bj = j; }   // smallest j at the max
      }
      // wave max (bit-exact: max is order-independent)
      float wm = bestv;
      wm = dppmaxf<0x111>(wm);   // row_shr:1
      wm = dppmaxf<0x112>(wm);   // row_shr:2
      wm = dppmaxf<0x114>(wm);   // row_shr:4
      wm = dppmaxf<0x118>(wm);   // row_shr:8
      wm = dppmaxf<0x142>(wm);   // row_bcast15
      wm = dppmaxf<0x143>(wm);   // row_bcast31
      const unsigned wmax_bits = (unsigned)__builtin_amdgcn_readlane(__float_as_int(wm), 63);
      const float wmax = __uint_as_float(wmax_bits);
      // min index among matching lanes, encoded as max(8191 - idx)
      unsigned enc = (bestv == wmax) ? (unsigned)(8191 - (bj * 512 + t)) : 0u;
      enc = dppmaxu<0x111>(enc);
      enc = dppmaxu<0x112>(enc);
      enc = dppmaxu<0x114>(enc);
      enc = dppmaxu<0x118>(enc);
      enc = dppmaxu<0x142>(enc);
      enc = dppmaxu<0x143>(enc);
      const unsigned widx_enc = (unsigned)__builtin_amdgcn_readlane((int)enc, 63);
      if (lane == 0)
        s_wb[par][wv] = ((unsigned long long)wmax_bits << 32) | widx_enc;
      __syncthreads();
      unsigned long long gk = s_wb[par][0];
#pragma unroll
      for (int i = 1; i < 8; ++i) {
        unsigned long long ki = s_wb[par][i]; if (ki > gk) gk = ki;
      }
      const int bi = 8191 - (int)(gk & 0xffffull);
      cx = sx[bi]; cy = sy[bi]; cz = sz[bi];
      if (t == 0) {
        unsigned* o = outp + s*3;
        __hip_atomic_store(o+0, __float_as_uint(cx), __ATOMIC_RELAXED, __HIP_MEMORY_SCOPE_AGENT);
        __hip_atomic_store(o+1, __float_as_uint(cy), __ATOMIC_RELAXED, __HIP_MEMORY_SCOPE_AGENT);
        __hip_atomic_store(o+2, __float_as_uint(cz), __ATOMIC_RELAXED, __HIP_MEMORY_SCOPE_AGENT);
      }
    }
  } else {
    // --------------------- persistent BQ+stats1 workers ---------------------
    const int wid  = ((int)blockIdx.x - NFPS) * 8 + (threadIdx.x >> 6);
    const int lane = threadIdx.x & 63;
    float wrow[6];
#pragma unroll
    for (int c = 0; c < 6; ++c) wrow[c] = w1[lane*6 + c];
    const float bv = b1[lane];
    const float R2 = 0.04f;
    float itemS = 0.f, itemQ = 0.f;   // per-wave accumulated BN1 partials

    for (int item = wid; item < NB*NS; item += NWAVES) {
      const int s = item >> 4;        // s-major: early centroids first
      const int b = item & 15;
      const int gw = (b << 10) + s;
      const float* base  = xyz + (size_t)b * NN * 3;
      const float* pbase = pts + (size_t)b * NN * 3;
      float* out = x0 + (size_t)gw * (NK*6);

      const unsigned* cp = (const unsigned*)(new_xyz + (size_t)gw * 3);
      float cx, cy, cz;
      for (;;) {
        unsigned ux = __hip_atomic_load(cp+0, __ATOMIC_RELAXED, __HIP_MEMORY_SCOPE_AGENT);
        unsigned uy = __hip_atomic_load(cp+1, __ATOMIC_RELAXED, __HIP_MEMORY_SCOPE_AGENT);
        unsigned uz = __hip_atomic_load(cp+2, __ATOMIC_RELAXED, __HIP_MEMORY_SCOPE_AGENT);
        if (ux != 0xFFFFFFFFu && uy != 0xFFFFFFFFu && uz != 0xFFFFFFFFu) {
          cx = __uint_as_float(ux); cy = __uint_as_float(uy); cz = __uint_as_float(uz);
          break;
        }
        __builtin_amdgcn_s_sleep(16);
      }

      // ---- ball query (bit-identical numerics) ----
      const float t1 = __fadd_rn(__fadd_rn(__fmul_rn(cx,cx),__fmul_rn(cy,cy)),__fmul_rn(cz,cz));
      int count = 0, pfirst = 0;
      for (int n0 = 0; n0 < NN; n0 += 64) {
        const int p = n0 + lane;
        const float ax = base[p*3], ay = base[p*3+1], az = base[p*3+2];
        const float t2 = __fadd_rn(__fadd_rn(__fmul_rn(ax,ax),__fmul_rn(ay,ay)),__fmul_rn(az,az));
        const float dt = __fmaf_rn(cz, az, __fmaf_rn(cy, ay, __fmul_rn(cx, ax)));
        const float sq = __fadd_rn(__fsub_rn(t1, __fmul_rn(2.0f,dt)), t2);
        const bool keep = !(sq > R2);
        const unsigned long long mask = __ballot(keep);
        const int slot = count + __popcll(mask & ((1ull<<lane)-1ull));
        if (keep && slot < NK) {
          float* o = out + slot*6;
          o[0]=ax-cx; o[1]=ay-cy; o[2]=az-cz;
          o[3]=pbase[p*3]; o[4]=pbase[p*3+1]; o[5]=pbase[p*3+2];
        }
        if (count == 0 && mask != 0ull) pfirst = n0 + (__ffsll((unsigned long long)mask) - 1);
        count += __popcll(mask);
        if (count >= NK) break;
      }
      if (count < NK) {
        const float* fx = base + (size_t)pfirst*3;
        const float* fp = pbase + (size_t)pfirst*3;
        const float a0 = fx[0]-cx, a1 = fx[1]-cy, a2 = fx[2]-cz;
        const float a3 = fp[0], a4 = fp[1], a5 = fp[2];
        for (int sl = count + lane; sl < NK; sl += 64) {
          float* o = out + sl*6;
          o[0]=a0;o[1]=a1;o[2]=a2;o[3]=a3;o[4]=a4;o[5]=a5;
        }
      }

      // ---- stats1 for this item's 32 rows (lane = channel) ----
      __threadfence_block();
      float sAcc = 0.f, qAcc = 0.f;
#pragma unroll 4
      for (int k = 0; k < NK; ++k) {
        const float* row = out + k*6;
        float z = bv;
#pragma unroll
        for (int c = 0; c < 6; ++c) z = fmaf(row[c], wrow[c], z);
        sAcc += z;
        qAcc = fmaf(z, z, qAcc);
      }
      itemS += sAcc;
      itemQ += qAcc;
    }
    // one part row per wave: [1920][128]
    part[(size_t)wid*128 + lane]      = itemS;
    part[(size_t)wid*128 + 64 + lane] = itemQ;
  }
}

// ---------------------------------------------------------------------------
// BN finalize (nrows = partial-row count).
// ---------------------------------------------------------------------------
__global__ __launch_bounds__(256) void finalize_kernel(const float* __restrict__ part,
                                                       int nrows, int rowstride, int C,
                                                       const float* __restrict__ g,
                                                       const float* __restrict__ be,
                                                       float* __restrict__ ab) {
  const int ch = blockIdx.x;
  const int t = threadIdx.x;
  const int qo = rowstride >> 1;
  double s = 0.0, q = 0.0;
  for (int wv = t; wv < nrows; wv += 256) {
    s += (double)part[(size_t)wv*rowstride + ch];
    q += (double)part[(size_t)wv*rowstride + qo + ch];
  }
#pragma unroll
  for (int off = 32; off >= 1; off >>= 1) {
    s += __shfl_down(s, off, 64);
    q += __shfl_down(q, off, 64);
  }
  __shared__ double ls[4], lq[4];
  if ((t & 63) == 0) { ls[t>>6] = s; lq[t>>6] = q; }
  __syncthreads();
  if (t == 0) {
    double S = ls[0]+ls[1]+ls[2]+ls[3];
    double Q = lq[0]+lq[1]+lq[2]+lq[3];
    double mean = S / (double)NR;
    double var  = Q / (double)NR - mean*mean;
    double inv  = 1.0 / sqrt(var + 1e-5);
    double gg   = (double)g[ch];
    ab[ch]     = (float)(gg * inv);
    ab[C + ch] = (float)((double)be[ch] - mean * gg * inv);
  }
}

// ============================ MLP passes ============================

__device__ __forceinline__ void lean_h1(const float* __restrict__ xr,
                                        const float* __restrict__ w1,
                                        const float* __restrict__ b1,
                                        const float* __restrict__ ab1,
                                        float (&h)[64]) {
  float x[6];
#pragma unroll
  for (int c = 0; c < 6; ++c) x[c] = xr[c];
#pragma unroll
  for (int o = 0; o < 64; ++o) {
    float acc = b1[o];
#pragma unroll
    for (int c = 0; c < 6; ++c) acc = fmaf(x[c], w1[o*6+c], acc);
    h[o] = fmaxf(0.f, fmaf(acc, ab1[o], ab1[64+o]));
  }
}

// ---------------------------------------------------------------------------
// stats2 v2 (UNCHANGED from round 5 — proven): lane = OUTPUT channel, w2 row
// register-resident; per-wave LDS h-tile (stride 68); bf16 z2 store via
// lane-pair shfl; channel sums in 2 scalar regs.
// ---------------------------------------------------------------------------
__global__ __launch_bounds__(256) void stats2_store(const float* __restrict__ x0,
                                                    const float* __restrict__ w1,
                                                    const float* __restrict__ b1,
                                                    const float* __restrict__ ab1,
                                                    const float* __restrict__ w2,
                                                    const float* __restrict__ b2,
                                                    unsigned* __restrict__ z2u,
                                                    float* __restrict__ part) {
  const int t = threadIdx.x;
  const int lane = t & 63;
  const int wvi = t >> 6;
  __shared__ float hT[4][64*68];       // 69,632 B
  __shared__ float rS[4][64], rQ[4][64];

  const int row0 = ((int)blockIdx.x*4 + wvi) * 64;
  float* ht = hT[wvi];

  // ---- phase A: lane = row ----
  {
    float h[64];
    lean_h1(x0 + (size_t)(row0 + lane)*6, w1, b1, ab1, h);
    float4* hw = (float4*)(ht + lane*68);
#pragma unroll
    for (int c4 = 0; c4 < 16; ++c4)
      hw[c4] = make_float4(h[4*c4+0], h[4*c4+1], h[4*c4+2], h[4*c4+3]);
  }
  asm volatile("s_waitcnt lgkmcnt(0)" ::: "memory");

  // ---- phase B: lane = output channel o ----
  float w2r[64];
  {
    const float4* wr = (const float4*)(w2 + (size_t)lane*64);
#pragma unroll
    for (int c4 = 0; c4 < 16; ++c4) {
      float4 v = wr[c4];
      w2r[4*c4+0]=v.x; w2r[4*c4+1]=v.y; w2r[4*c4+2]=v.z; w2r[4*c4+3]=v.w;
    }
  }
  const float bz = b2[lane];
  float accS = 0.f, accQ = 0.f;
#pragma unroll 2
  for (int r = 0; r < 64; ++r) {
    const float4* hr = (const float4*)(ht + r*68);
    float z = bz;
#pragma unroll
    for (int c4 = 0; c4 < 16; ++c4) {
      float4 hv = hr[c4];                 // uniform-address broadcast
      z = fmaf(hv.x, w2r[4*c4+0], z);
      z = fmaf(hv.y, w2r[4*c4+1], z);
      z = fmaf(hv.z, w2r[4*c4+2], z);
      z = fmaf(hv.w, w2r[4*c4+3], z);
    }
    accS += z; accQ = fmaf(z, z, accQ);
    const float zp = __shfl_xor(z, 1, 64);
    const unsigned word = (lane & 1) ? pack_bf2(zp, z) : pack_bf2(z, zp);
    if ((lane & 1) == 0)
      z2u[(size_t)(row0 + r)*32 + (lane >> 1)] = word;
  }
  rS[wvi][lane] = accS; rQ[wvi][lane] = accQ;
  __syncthreads();
  if (t < 64)
    part[(size_t)blockIdx.x*128 + t] = rS[0][t]+rS[1][t]+rS[2][t]+rS[3][t];
  else if (t < 128) {
    const int c = t - 64;
    part[(size_t)blockIdx.x*128 + 64 + c] = rQ[0][c]+rQ[1][c]+rQ[2][c]+rQ[3][c];
  }
}

// ---------------------------------------------------------------------------
// stats3 v2 (UNCHANGED from round 5 — proven): lane holds w3 rows o=lane and
// o=lane+64 in VGPRs; per-wave 64 rows = 2 pool groups; register pooling.
// ---------------------------------------------------------------------------
__global__ __launch_bounds__(256) void stats3_fused(const unsigned* __restrict__ z2u,
                                                    const float* __restrict__ ab,
                                                    const float* __restrict__ w,
                                                    const float* __restrict__ bias,
                                                    float* __restrict__ part,
                                                    float* __restrict__ kmx,
                                                    float* __restrict__ kmn) {
  const int t = threadIdx.x;
  const int lane = t & 63;
  const int wvi = t >> 6;
  __shared__ float hT[4][64*68];       // 69,632 B
  __shared__ float rS[4][128], rQ[4][128];

  const int row0 = ((int)blockIdx.x*4 + wvi) * 64;
  float* ht = hT[wvi];

  // ---- phase A: lane = row; bn2+relu unpack ----
  {
    const uint4* zr = (const uint4*)(z2u + (size_t)(row0 + lane) * 32);
    float h[64];
#pragma unroll
    for (int i = 0; i < 8; ++i) {
      uint4 v = zr[i];
      const int c = i*8;
      h[c+0]=fmaxf(0.f,fmaf(bf_lo(v.x),ab[c+0],ab[64+c+0]));
      h[c+1]=fmaxf(0.f,fmaf(bf_hi(v.x),ab[c+1],ab[64+c+1]));
      h[c+2]=fmaxf(0.f,fmaf(bf_lo(v.y),ab[c+2],ab[64+c+2]));
      h[c+3]=fmaxf(0.f,fmaf(bf_hi(v.y),ab[c+3],ab[64+c+3]));
      h[c+4]=fmaxf(0.f,fmaf(bf_lo(v.z),ab[c+4],ab[64+c+4]));
      h[c+5]=fmaxf(0.f,fmaf(bf_hi(v.z),ab[c+5],ab[64+c+5]));
      h[c+6]=fmaxf(0.f,fmaf(bf_lo(v.w),ab[c+6],ab[64+c+6]));
      h[c+7]=fmaxf(0.f,fmaf(bf_hi(v.w),ab[c+7],ab[64+c+7]));
    }
    float4* hw = (float4*)(ht + lane*68);
#pragma unroll
    for (int c4 = 0; c4 < 16; ++c4)
      hw[c4] = make_float4(h[4*c4+0], h[4*c4+1], h[4*c4+2], h[4*c4+3]);
  }
  asm volatile("s_waitcnt lgkmcnt(0)" ::: "memory");

  // ---- phase B: lane = output channel; chunks o=lane, o=lane+64 ----
  float w3a[64], w3b[64];
  {
    const float4* wra = (const float4*)(w + (size_t)lane*64);
    const float4* wrb = (const float4*)(w + (size_t)(lane+64)*64);
#pragma unroll
    for (int c4 = 0; c4 < 16; ++c4) {
      float4 va = wra[c4];
      w3a[4*c4+0]=va.x; w3a[4*c4+1]=va.y; w3a[4*c4+2]=va.z; w3a[4*c4+3]=va.w;
      float4 vb = wrb[c4];
      w3b[4*c4+0]=vb.x; w3b[4*c4+1]=vb.y; w3b[4*c4+2]=vb.z; w3b[4*c4+3]=vb.w;
    }
  }
  const float bza = bias[lane], bzb = bias[64+lane];
  float sA = 0.f, qA = 0.f, sB = 0.f, qB = 0.f;
#pragma unroll 1
  for (int g2 = 0; g2 < 2; ++g2) {
    float mA = -1e30f, nA = 1e30f, mB = -1e30f, nB = 1e30f;
#pragma unroll 2
    for (int r = g2*32; r < g2*32 + 32; ++r) {
      const float4* hr = (const float4*)(ht + r*68);
      float za = bza, zb = bzb;
#pragma unroll
      for (int c4 = 0; c4 < 16; ++c4) {
        float4 hv = hr[c4];               // uniform-address broadcast
        za = fmaf(hv.x, w3a[4*c4+0], za);
        za = fmaf(hv.y, w3a[4*c4+1], za);
        za = fmaf(hv.z, w3a[4*c4+2], za);
        za = fmaf(hv.w, w3a[4*c4+3], za);
        zb = fmaf(hv.x, w3b[4*c4+0], zb);
        zb = fmaf(hv.y, w3b[4*c4+1], zb);
        zb = fmaf(hv.z, w3b[4*c4+2], zb);
        zb = fmaf(hv.w, w3b[4*c4+3], zb);
      }
      mA = fmaxf(mA, za); nA = fminf(nA, za); sA += za; qA = fmaf(za, za, qA);
      mB = fmaxf(mB, zb); nB = fminf(nB, zb); sB += zb; qB = fmaf(zb, zb, qB);
    }
    const size_t group = (size_t)(((int)blockIdx.x*4 + wvi)*2 + g2);
    kmx[group*128 + lane]      = mA;
    kmx[group*128 + 64 + lane] = mB;
    kmn[group*128 + lane]      = nA;
    kmn[group*128 + 64 + lane] = nB;
  }
  rS[wvi][lane] = sA; rS[wvi][64+lane] = sB;
  rQ[wvi][lane] = qA; rQ[wvi][64+lane] = qB;
  __syncthreads();
  if (t < 128)
    part[(size_t)blockIdx.x*256 + t] = rS[0][t]+rS[1][t]+rS[2][t]+rS[3][t];
  else {
    const int c = t - 128;
    part[(size_t)blockIdx.x*256 + 128 + c] = rQ[0][c]+rQ[1][c]+rQ[2][c]+rQ[3][c];
  }
}

// bn3 (r7-validated): out = relu(a*sel + b), sel = a>=0 ? kmax : kmin
__global__ __launch_bounds__(128) void bn3_kernel(const float* __restrict__ kmx,
                                                  const float* __restrict__ kmn,
                                                  const float* __restrict__ ab,
                                                  float* __restrict__ outp) {
  const int g = blockIdx.x;
  const int c = threadIdx.x;
  const float a = ab[c], bsh = ab[128 + c];
  const float v = (a >= 0.f) ? kmx[(size_t)g*128 + c] : kmn[(size_t)g*128 + c];
  outp[(size_t)g*128 + c] = fmaxf(0.f, fmaf(v, a, bsh));
}

// ============================ launcher ============================

extern "C" void kernel_launch(void* const* d_in, const int* in_sizes, int n_in,
                              void* d_out, int out_size, void* d_ws, size_t ws_size,
                              hipStream_t stream) {
  (void)in_sizes; (void)n_in; (void)out_size; (void)ws_size;
  const float* xyz = (const float*)d_in[0];
  const float* pts = (const float*)d_in[1];
  const float* w1  = (const float*)d_in[2];
  const float* b1  = (const float*)d_in[3];
  const float* g1  = (const float*)d_in[4];
  const float* be1 = (const float*)d_in[5];
  const float* w2  = (const float*)d_in[6];
  const float* b2  = (const float*)d_in[7];
  const float* g2  = (const float*)d_in[8];
  const float* be2 = (const float*)d_in[9];
  const float* w3  = (const float*)d_in[10];
  const float* b3  = (const float*)d_in[11];
  const float* g3  = (const float*)d_in[12];
  const float* be3 = (const float*)d_in[13];

  float* out = (float*)d_out;
  float* new_xyz    = out;
  float* new_points = out + NB*NS*3;

  // ws: x0 12.6MB | part 8.4MB | ab 2KB | z2u 67MB | kmx 8MB | kmn 8MB ~ 104MB
  float* ws = (float*)d_ws;
  float* x0   = ws;                               // NR*6
  float* part = x0 + (size_t)NR*6;                // up to 2048*256 floats
  float* ab   = part + 2097152;                   // 512
  float* ab1  = ab;
  float* ab2  = ab + 128;
  float* ab3  = ab + 256;
  unsigned* z2u = (unsigned*)(ab + 512);          // NR*32 u32
  float* kmx = (float*)(z2u + (size_t)NR*32);     // 16384*128
  float* kmn = kmx + (size_t)16384*128;           // 16384*128
  const int NBLK = NR/256;                        // 2048

  // NaN-poison new_xyz: the fused kernel's publish sentinel.
  (void)hipMemsetAsync(new_xyz, 0xFF, (size_t)NB*NS*3*sizeof(float), stream);

  // fused FPS (blocks 0..15) + persistent ballquery/stats1 workers (16..255);
  // part written per-WAVE: [1920][128] (sum | sumsq)
  hipLaunchKernelGGL(fps_bq_s1_kernel, dim3(NFPS + NWORK), dim3(512), 0, stream,
                     xyz, pts, w1, b1, new_xyz, x0, part);

  hipLaunchKernelGGL(finalize_kernel, dim3(64), dim3(256), 0, stream, part, NWAVES, 128, 64, g1, be1, ab1);
  hipLaunchKernelGGL(stats2_store, dim3(NBLK), dim3(256), 0, stream,
                     x0, w1, b1, ab1, w2, b2, z2u, part);
  hipLaunchKernelGGL(finalize_kernel, dim3(64), dim3(256), 0, stream, part, NBLK, 128, 64, g2, be2, ab2);
  hipLaunchKernelGGL(stats3_fused, dim3(NBLK), dim3(256), 0, stream,
                     z2u, ab2, w3, b3, part, kmx, kmn);
  hipLaunchKernelGGL(finalize_kernel, dim3(128), dim3(256), 0, stream, part, NBLK, 256, 128, g3, be3, ab3);
  hipLaunchKernelGGL(bn3_kernel, dim3(NB*NS), dim3(128), 0, stream, kmx, kmn, ab3, new_points);
}